// Round 1
// baseline (3320.898 us; speedup 1.0000x reference)
//
#include <hip/hip_runtime.h>
#include <math.h>

#define N_NODES 2048
#define DIM     512
#define HEADS   8
#define FFDIM   2048
#define EDIM    64
#define PMAX    4
#define NEDGE   32768

#define BM 64
#define BN 64
#define BK 16

// ---------------------------------------------------------------------------
// LayerNorm: one block (256 threads) per row of 512 floats.
// ---------------------------------------------------------------------------
__global__ __launch_bounds__(256)
void ln_kernel(const float* __restrict__ x, const float* __restrict__ g,
               const float* __restrict__ beta, float* __restrict__ out) {
    const int row = blockIdx.x;
    const int t = threadIdx.x;
    const float* xr = x + (size_t)row * DIM;
    const float v0 = xr[t];
    const float v1 = xr[t + 256];
    __shared__ float red[4];
    const int lane = t & 63, wid = t >> 6;

    float s = v0 + v1;
    #pragma unroll
    for (int o = 32; o > 0; o >>= 1) s += __shfl_xor(s, o);
    if (lane == 0) red[wid] = s;
    __syncthreads();
    const float mu = (red[0] + red[1] + red[2] + red[3]) * (1.0f / DIM);
    __syncthreads();

    const float d0 = v0 - mu, d1 = v1 - mu;
    float vs = d0 * d0 + d1 * d1;
    #pragma unroll
    for (int o = 32; o > 0; o >>= 1) vs += __shfl_xor(vs, o);
    if (lane == 0) red[wid] = vs;
    __syncthreads();
    const float var = (red[0] + red[1] + red[2] + red[3]) * (1.0f / DIM);
    const float inv = 1.0f / sqrtf(var + 1e-5f);

    out[(size_t)row * DIM + t]       = d0 * inv * g[t] + beta[t];
    out[(size_t)row * DIM + t + 256] = d1 * inv * g[t + 256] + beta[t + 256];
}

// ---------------------------------------------------------------------------
// d[e][h*4+p] = sum_f edge_attr[e][f] * edge_vec[h][p][f]   (layout [E][32])
// ---------------------------------------------------------------------------
__global__ __launch_bounds__(256)
void edge_d_kernel(const float* __restrict__ edge_attr,
                   const float* __restrict__ edge_vec,
                   float* __restrict__ dout) {
    __shared__ float ev[HEADS * PMAX * EDIM]; // 2048 floats
    const int t = threadIdx.x;
    for (int i = t; i < HEADS * PMAX * EDIM; i += 256) ev[i] = edge_vec[i];
    __syncthreads();

    const int e = blockIdx.x * 256 + t;
    float acc[32];
    #pragma unroll
    for (int i = 0; i < 32; i++) acc[i] = 0.0f;

    const float4* ea = (const float4*)(edge_attr + (size_t)e * EDIM);
    #pragma unroll
    for (int f4 = 0; f4 < EDIM / 4; f4++) {
        const float4 a = ea[f4];
        #pragma unroll
        for (int hp = 0; hp < 32; hp++) {
            const float4 v = ((const float4*)(ev + hp * EDIM))[f4];
            acc[hp] += a.x * v.x + a.y * v.y + a.z * v.z + a.w * v.w;
        }
    }
    float* o = dout + (size_t)e * 32;
    #pragma unroll
    for (int i = 0; i < 32; i++) o[i] = acc[i];
}

// ---------------------------------------------------------------------------
// fp32 tiled GEMM bodies. 64x64 tile, BK=16, 256 threads, 4x4 micro-tile.
// A row-major [M,K]; NN: B row-major [K,N]; NT: B row-major [N,K] (B^T).
// ---------------------------------------------------------------------------
__device__ __forceinline__
void gemm_nn_body(const float* __restrict__ A, int lda,
                  const float* __restrict__ B, int ldb,
                  float* __restrict__ C, int ldc, int K,
                  const float* __restrict__ bias,
                  const float* __restrict__ res, int ldr,
                  int gelu_flag) {
    __shared__ float As[BM][BK + 1];   // +1 pad: kills 4-way bank conflict on col reads
    __shared__ float Bs[BK][BN];
    const int t = threadIdx.x;
    const int tx = t & 15, ty = t >> 4;
    const int rowBase = blockIdx.x * BM, colBase = blockIdx.y * BN;
    const int aRow = t >> 2,  aCol = (t & 3) * 4;
    const int bRow = t >> 4,  bCol = (t & 15) * 4;
    float acc[4][4] = {};
    const float* Aptr = A + (size_t)(rowBase + aRow) * lda + aCol;
    const float* Bptr = B + (size_t)bRow * ldb + colBase + bCol;

    for (int k0 = 0; k0 < K; k0 += BK) {
        const float4 av = *(const float4*)(Aptr + k0);
        const float4 bv = *(const float4*)(Bptr + (size_t)k0 * ldb);
        __syncthreads();
        As[aRow][aCol]     = av.x; As[aRow][aCol + 1] = av.y;
        As[aRow][aCol + 2] = av.z; As[aRow][aCol + 3] = av.w;
        *(float4*)&Bs[bRow][bCol] = bv;
        __syncthreads();
        #pragma unroll
        for (int kk = 0; kk < BK; kk++) {
            const float a0 = As[ty * 4 + 0][kk];
            const float a1 = As[ty * 4 + 1][kk];
            const float a2 = As[ty * 4 + 2][kk];
            const float a3 = As[ty * 4 + 3][kk];
            const float4 b4 = *(const float4*)&Bs[kk][tx * 4];
            acc[0][0] += a0 * b4.x; acc[0][1] += a0 * b4.y; acc[0][2] += a0 * b4.z; acc[0][3] += a0 * b4.w;
            acc[1][0] += a1 * b4.x; acc[1][1] += a1 * b4.y; acc[1][2] += a1 * b4.z; acc[1][3] += a1 * b4.w;
            acc[2][0] += a2 * b4.x; acc[2][1] += a2 * b4.y; acc[2][2] += a2 * b4.z; acc[2][3] += a2 * b4.w;
            acc[3][0] += a3 * b4.x; acc[3][1] += a3 * b4.y; acc[3][2] += a3 * b4.z; acc[3][3] += a3 * b4.w;
        }
    }
    #pragma unroll
    for (int i = 0; i < 4; i++) {
        const int r = rowBase + ty * 4 + i;
        #pragma unroll
        for (int j = 0; j < 4; j++) {
            const int c = colBase + tx * 4 + j;
            float v = acc[i][j];
            if (bias) v += bias[c];
            if (gelu_flag) v = 0.5f * v * (1.0f + erff(v * 0.70710678118654752f));
            if (res) v += res[(size_t)r * ldr + c];
            C[(size_t)r * ldc + c] = v;
        }
    }
}

__device__ __forceinline__
void gemm_nt_body(const float* __restrict__ A, int lda,
                  const float* __restrict__ B, int ldb,   // B is [N,K]
                  float* __restrict__ C, int ldc, int K) {
    __shared__ float As[BM][BK + 1];
    __shared__ float Bs[BN][BK + 1];
    const int t = threadIdx.x;
    const int tx = t & 15, ty = t >> 4;
    const int rowBase = blockIdx.x * BM, colBase = blockIdx.y * BN;
    const int lRow = t >> 2, lCol = (t & 3) * 4;
    float acc[4][4] = {};
    const float* Aptr = A + (size_t)(rowBase + lRow) * lda + lCol;
    const float* Bptr = B + (size_t)(colBase + lRow) * ldb + lCol;

    for (int k0 = 0; k0 < K; k0 += BK) {
        const float4 av = *(const float4*)(Aptr + k0);
        const float4 bv = *(const float4*)(Bptr + k0);
        __syncthreads();
        As[lRow][lCol]     = av.x; As[lRow][lCol + 1] = av.y;
        As[lRow][lCol + 2] = av.z; As[lRow][lCol + 3] = av.w;
        Bs[lRow][lCol]     = bv.x; Bs[lRow][lCol + 1] = bv.y;
        Bs[lRow][lCol + 2] = bv.z; Bs[lRow][lCol + 3] = bv.w;
        __syncthreads();
        #pragma unroll
        for (int kk = 0; kk < BK; kk++) {
            const float a0 = As[ty * 4 + 0][kk];
            const float a1 = As[ty * 4 + 1][kk];
            const float a2 = As[ty * 4 + 2][kk];
            const float a3 = As[ty * 4 + 3][kk];
            const float b0 = Bs[tx * 4 + 0][kk];
            const float b1 = Bs[tx * 4 + 1][kk];
            const float b2 = Bs[tx * 4 + 2][kk];
            const float b3 = Bs[tx * 4 + 3][kk];
            acc[0][0] += a0 * b0; acc[0][1] += a0 * b1; acc[0][2] += a0 * b2; acc[0][3] += a0 * b3;
            acc[1][0] += a1 * b0; acc[1][1] += a1 * b1; acc[1][2] += a1 * b2; acc[1][3] += a1 * b3;
            acc[2][0] += a2 * b0; acc[2][1] += a2 * b1; acc[2][2] += a2 * b2; acc[2][3] += a2 * b3;
            acc[3][0] += a3 * b0; acc[3][1] += a3 * b1; acc[3][2] += a3 * b2; acc[3][3] += a3 * b3;
        }
    }
    #pragma unroll
    for (int i = 0; i < 4; i++) {
        const int r = rowBase + ty * 4 + i;
        #pragma unroll
        for (int j = 0; j < 4; j++) {
            const int c = colBase + tx * 4 + j;
            C[(size_t)r * ldc + c] = acc[i][j];
        }
    }
}

__global__ __launch_bounds__(256)
void k_gemm_nn(const float* __restrict__ A, int lda,
               const float* __restrict__ B, int ldb,
               float* __restrict__ C, int ldc, int K,
               const float* __restrict__ bias,
               const float* __restrict__ res, int ldr, int gelu_flag) {
    gemm_nn_body(A, lda, B, ldb, C, ldc, K, bias, res, ldr, gelu_flag);
}

__global__ __launch_bounds__(256)
void k_gemm_nt(const float* __restrict__ A, int lda,
               const float* __restrict__ B, int ldb,
               float* __restrict__ C, int ldc, int K) {
    gemm_nt_body(A, lda, B, ldb, C, ldc, K);
}

// Q/K/V projection for head h: grid.z in {0,1,2} selects Wq/Wk/Wv.
__global__ __launch_bounds__(256)
void k_gemm_qkv(const float* __restrict__ xln,
                const float* __restrict__ Wq, const float* __restrict__ Wk,
                const float* __restrict__ Wv,
                const float* __restrict__ bq, const float* __restrict__ bk,
                const float* __restrict__ bv,
                float* __restrict__ Qh, float* __restrict__ Kh,
                float* __restrict__ Vh, int h) {
    const int z = blockIdx.z;
    const float* B;  const float* bias;  float* C;
    if (z == 0)      { B = Wq + (size_t)h * DIM * DIM; bias = bq + h * DIM; C = Qh; }
    else if (z == 1) { B = Wk + (size_t)h * DIM * DIM; bias = bk + h * DIM; C = Kh; }
    else             { B = Wv + (size_t)h * DIM * DIM; bias = bv + h * DIM; C = Vh; }
    gemm_nn_body(xln, DIM, B, DIM, C, DIM, DIM, bias, nullptr, 0, 0);
}

// ---------------------------------------------------------------------------
// In-place: S[i][j] = softmax_j( S[i][j]*scale + b[i][j] + c_h(i,j) )
// c_h via path gather. One block per row.
// ---------------------------------------------------------------------------
__global__ __launch_bounds__(256)
void bias_softmax(float* __restrict__ S, const float* __restrict__ b,
                  const int* __restrict__ path_idx,
                  const int* __restrict__ path_len,
                  const float* __restrict__ d, int h) {
    const int i = blockIdx.x;
    const int t = threadIdx.x;
    const float scale = 0.04419417382415922f; // 1/sqrt(512)
    const int lane = t & 63, wid = t >> 6;
    __shared__ float redm[4];
    __shared__ float reds[4];

    float v[8];
    float m = -1e30f;
    #pragma unroll
    for (int k = 0; k < 8; k++) {
        const int j = t + k * 256;
        const size_t idx = (size_t)i * N_NODES + j;
        float val = S[idx] * scale + b[idx];
        const int len = path_len[idx];
        if (len > 0) {
            const int4 pi = ((const int4*)path_idx)[idx];
            float csum = d[(size_t)pi.x * 32 + h * 4 + 0];
            if (len > 1) csum += d[(size_t)pi.y * 32 + h * 4 + 1];
            if (len > 2) csum += d[(size_t)pi.z * 32 + h * 4 + 2];
            if (len > 3) csum += d[(size_t)pi.w * 32 + h * 4 + 3];
            val += csum / (float)len;
        }
        v[k] = val;
        m = fmaxf(m, val);
    }
    #pragma unroll
    for (int o = 32; o > 0; o >>= 1) m = fmaxf(m, __shfl_xor(m, o));
    if (lane == 0) redm[wid] = m;
    __syncthreads();
    m = fmaxf(fmaxf(redm[0], redm[1]), fmaxf(redm[2], redm[3]));

    float s = 0.0f;
    #pragma unroll
    for (int k = 0; k < 8; k++) { v[k] = expf(v[k] - m); s += v[k]; }
    #pragma unroll
    for (int o = 32; o > 0; o >>= 1) s += __shfl_xor(s, o);
    if (lane == 0) reds[wid] = s;
    __syncthreads();
    s = reds[0] + reds[1] + reds[2] + reds[3];
    const float inv = 1.0f / s;
    #pragma unroll
    for (int k = 0; k < 8; k++)
        S[(size_t)i * N_NODES + t + k * 256] = v[k] * inv;
}

// ---------------------------------------------------------------------------
extern "C" void kernel_launch(void* const* d_in, const int* in_sizes, int n_in,
                              void* d_out, int out_size, void* d_ws, size_t ws_size,
                              hipStream_t stream) {
    const float* x         = (const float*)d_in[0];
    const float* edge_attr = (const float*)d_in[1];
    const float* b         = (const float*)d_in[2];
    const int*   path_idx  = (const int*)d_in[3];
    const int*   path_len  = (const int*)d_in[4];
    const float* Wq = (const float*)d_in[5];  const float* bq = (const float*)d_in[6];
    const float* Wk = (const float*)d_in[7];  const float* bk = (const float*)d_in[8];
    const float* Wv = (const float*)d_in[9];  const float* bv = (const float*)d_in[10];
    const float* edge_vec = (const float*)d_in[11];
    const float* Wo = (const float*)d_in[12]; const float* bo = (const float*)d_in[13];
    const float* ln1g = (const float*)d_in[14]; const float* ln1b = (const float*)d_in[15];
    const float* ln2g = (const float*)d_in[16]; const float* ln2b = (const float*)d_in[17];
    const float* W1 = (const float*)d_in[18]; const float* b1 = (const float*)d_in[19];
    const float* W2 = (const float*)d_in[20]; const float* b2 = (const float*)d_in[21];
    float* out = (float*)d_out;

    // workspace layout (floats)
    float* ws = (float*)d_ws;
    size_t off = 0;
    float* xln   = ws + off; off += (size_t)N_NODES * DIM;          // 4 MB
    float* Qh    = ws + off; off += (size_t)N_NODES * DIM;          // 4 MB
    float* Kh    = ws + off; off += (size_t)N_NODES * DIM;          // 4 MB
    float* Vh    = ws + off; off += (size_t)N_NODES * DIM;          // 4 MB
    float* dbuf  = ws + off; off += (size_t)NEDGE * 32;             // 4 MB
    float* S     = ws + off; off += (size_t)N_NODES * N_NODES;      // 16.8 MB
    float* mh    = ws + off; off += (size_t)N_NODES * HEADS * DIM;  // 33.6 MB
    float* x1    = ws + off; off += (size_t)N_NODES * DIM;          // 4 MB
    float* h2    = ws + off; off += (size_t)N_NODES * DIM;          // 4 MB
    float* ffmid = ws + off; off += (size_t)N_NODES * FFDIM;        // 16.8 MB
    (void)ws_size; (void)in_sizes; (void)n_in; (void)out_size;

    // 1) LN1
    ln_kernel<<<N_NODES, 256, 0, stream>>>(x, ln1g, ln1b, xln);
    // 2) edge dot table d[e][h*4+p]
    edge_d_kernel<<<NEDGE / 256, 256, 0, stream>>>(edge_attr, edge_vec, dbuf);

    // 3) per-head attention
    for (int h = 0; h < HEADS; h++) {
        dim3 gqkv(N_NODES / BM, DIM / BN, 3);
        k_gemm_qkv<<<gqkv, 256, 0, stream>>>(xln, Wq, Wk, Wv, bq, bk, bv, Qh, Kh, Vh, h);
        dim3 gs(N_NODES / BM, N_NODES / BN);
        k_gemm_nt<<<gs, 256, 0, stream>>>(Qh, DIM, Kh, DIM, S, N_NODES, DIM);
        bias_softmax<<<N_NODES, 256, 0, stream>>>(S, b, path_idx, path_len, dbuf, h);
        dim3 gp(N_NODES / BM, DIM / BN);
        // write O_h directly into the concatenated mh buffer [N, H*D]
        k_gemm_nn<<<gp, 256, 0, stream>>>(S, N_NODES, Vh, DIM, mh + (size_t)h * DIM,
                                          HEADS * DIM, N_NODES, nullptr, nullptr, 0, 0);
    }

    // 4) output projection + residual: x1 = mh @ Wo + bo + x
    {
        dim3 g(N_NODES / BM, DIM / BN);
        k_gemm_nn<<<g, 256, 0, stream>>>(mh, HEADS * DIM, Wo, DIM, x1, DIM,
                                         HEADS * DIM, bo, x, DIM, 0);
    }
    // 5) LN2
    ln_kernel<<<N_NODES, 256, 0, stream>>>(x1, ln2g, ln2b, h2);
    // 6) FF1: gelu(h2 @ W1 + b1)
    {
        dim3 g(N_NODES / BM, FFDIM / BN);
        k_gemm_nn<<<g, 256, 0, stream>>>(h2, DIM, W1, FFDIM, ffmid, FFDIM,
                                         DIM, b1, nullptr, 0, 1);
    }
    // 7) FF2: out = ffmid @ W2 + b2 + x1
    {
        dim3 g(N_NODES / BM, DIM / BN);
        k_gemm_nn<<<g, 256, 0, stream>>>(ffmid, FFDIM, W2, DIM, out, DIM,
                                         FFDIM, b2, x1, DIM, 0);
    }
}

// Round 3
// 1660.296 us; speedup vs baseline: 2.0002x; 2.0002x over previous
//
#include <hip/hip_runtime.h>
#include <math.h>

#define N_NODES 2048
#define DIM     512
#define HEADS   8
#define FFDIM   2048
#define EDIM    64
#define PMAX    4
#define NEDGE   32768

// MFMA GEMM tile
#define BM 64
#define BN 64
#define BK 32

typedef __attribute__((ext_vector_type(8))) short bf16x8;           // MFMA A/B frag (8 bf16)
typedef __attribute__((ext_vector_type(8))) unsigned short u16x8;   // staging pack
typedef __attribute__((ext_vector_type(4))) float f32x4;            // MFMA acc

// ---------------------------------------------------------------------------
// LayerNorm: one block (256 threads) per row of 512 floats.
// ---------------------------------------------------------------------------
__global__ __launch_bounds__(256)
void ln_kernel(const float* __restrict__ x, const float* __restrict__ g,
               const float* __restrict__ beta, float* __restrict__ out) {
    const int row = blockIdx.x;
    const int t = threadIdx.x;
    const float* xr = x + (size_t)row * DIM;
    const float v0 = xr[t];
    const float v1 = xr[t + 256];
    __shared__ float red[4];
    const int lane = t & 63, wid = t >> 6;

    float s = v0 + v1;
    #pragma unroll
    for (int o = 32; o > 0; o >>= 1) s += __shfl_xor(s, o);
    if (lane == 0) red[wid] = s;
    __syncthreads();
    const float mu = (red[0] + red[1] + red[2] + red[3]) * (1.0f / DIM);
    __syncthreads();

    const float d0 = v0 - mu, d1 = v1 - mu;
    float vs = d0 * d0 + d1 * d1;
    #pragma unroll
    for (int o = 32; o > 0; o >>= 1) vs += __shfl_xor(vs, o);
    if (lane == 0) red[wid] = vs;
    __syncthreads();
    const float var = (red[0] + red[1] + red[2] + red[3]) * (1.0f / DIM);
    const float inv = 1.0f / sqrtf(var + 1e-5f);

    out[(size_t)row * DIM + t]       = d0 * inv * g[t] + beta[t];
    out[(size_t)row * DIM + t + 256] = d1 * inv * g[t + 256] + beta[t + 256];
}

// ---------------------------------------------------------------------------
// d[e][h*4+p] = sum_f edge_attr[e][f] * edge_vec[h][p][f]   (layout [E][32])
// ---------------------------------------------------------------------------
__global__ __launch_bounds__(256)
void edge_d_kernel(const float* __restrict__ edge_attr,
                   const float* __restrict__ edge_vec,
                   float* __restrict__ dout) {
    __shared__ float ev[HEADS * PMAX * EDIM]; // 2048 floats
    const int t = threadIdx.x;
    for (int i = t; i < HEADS * PMAX * EDIM; i += 256) ev[i] = edge_vec[i];
    __syncthreads();

    const int e = blockIdx.x * 256 + t;
    float acc[32];
    #pragma unroll
    for (int i = 0; i < 32; i++) acc[i] = 0.0f;

    const float4* ea = (const float4*)(edge_attr + (size_t)e * EDIM);
    #pragma unroll
    for (int f4 = 0; f4 < EDIM / 4; f4++) {
        const float4 a = ea[f4];
        #pragma unroll
        for (int hp = 0; hp < 32; hp++) {
            const float4 v = ((const float4*)(ev + hp * EDIM))[f4];
            acc[hp] += a.x * v.x + a.y * v.y + a.z * v.z + a.w * v.w;
        }
    }
    float* o = dout + (size_t)e * 32;
    #pragma unroll
    for (int i = 0; i < 32; i++) o[i] = acc[i];
}

// ---------------------------------------------------------------------------
// fp32 -> (bf16 hi, bf16 lo) split, truncation-based (pure bit ops + 1 sub).
// x = hi + lo + eps, |eps| <= 2^-14 |x|.
// ---------------------------------------------------------------------------
__device__ __forceinline__ void cvt8(float4 a, float4 b, u16x8* hi, u16x8* lo) {
    float v[8] = {a.x, a.y, a.z, a.w, b.x, b.y, b.z, b.w};
    u16x8 h, l;
    #pragma unroll
    for (int i = 0; i < 8; i++) {
        const unsigned int u = __float_as_uint(v[i]);
        h[i] = (unsigned short)(u >> 16);
        const float r = v[i] - __uint_as_float(u & 0xFFFF0000u);
        l[i] = (unsigned short)(__float_as_uint(r) >> 16);
    }
    *hi = h; *lo = l;
}

// ---------------------------------------------------------------------------
// bf16x3 MFMA GEMM (NT): C[M][N] = A[M][K] * B[N][K]^T  (both fp32 row-major)
// 64x64 tile, BK=32, 256 threads = 4 waves (2x2), wave tile 32x32 = 2x2 MFMA
// frags of 16x16x32. fp32 operands split to hi/lo bf16 planes in LDS; 3 MFMA
// passes per frag pair (hh + hl + lh) recover ~fp32 precision.
// biasMode: 0 none, 1 bias[col], 2 bias[row].
// ---------------------------------------------------------------------------
__device__ __forceinline__
void mgemm_body(const float* __restrict__ A, int lda,
                const float* __restrict__ B, int ldb,
                float* __restrict__ C, int ldc, int K,
                const float* __restrict__ bias, int biasMode,
                const float* __restrict__ res, int ldr, int gelu_flag) {
    __shared__ __attribute__((aligned(16))) unsigned short As_h[BM * BK];
    __shared__ __attribute__((aligned(16))) unsigned short As_l[BM * BK];
    __shared__ __attribute__((aligned(16))) unsigned short Bs_h[BN * BK];
    __shared__ __attribute__((aligned(16))) unsigned short Bs_l[BN * BK];

    const int t = threadIdx.x;
    const int l = t & 63;
    const int wave = t >> 6;
    const int wr = wave >> 1, wc = wave & 1;        // 2x2 wave grid
    const int rowBase = blockIdx.x * BM, colBase = blockIdx.y * BN;

    // staging: thread t loads 8 consecutive floats of row sRow (A and B tiles)
    const int sRow = t >> 2, sCol = (t & 3) * 8;
    const float* Ag = A + (size_t)(rowBase + sRow) * lda + sCol;
    const float* Bg = B + (size_t)(colBase + sRow) * ldb + sCol;

    f32x4 acc[2][2] = {};

    float4 pa0 = *(const float4*)(Ag);
    float4 pa1 = *(const float4*)(Ag + 4);
    float4 pb0 = *(const float4*)(Bg);
    float4 pb1 = *(const float4*)(Bg + 4);

    const int fr = l & 15;          // frag row/col within 16
    const int kg = (l >> 4) * 8;    // k-group start (elements)

    for (int k0 = 0; k0 < K; k0 += BK) {
        u16x8 ah, al, bh, bl;
        cvt8(pa0, pa1, &ah, &al);
        cvt8(pb0, pb1, &bh, &bl);
        __syncthreads();                       // prior frag reads done
        *(u16x8*)&As_h[sRow * BK + sCol] = ah; // wave writes contiguous 1KB: conflict-free
        *(u16x8*)&As_l[sRow * BK + sCol] = al;
        *(u16x8*)&Bs_h[sRow * BK + sCol] = bh;
        *(u16x8*)&Bs_l[sRow * BK + sCol] = bl;
        __syncthreads();
        if (k0 + BK < K) {                     // prefetch next tiles (hides HBM latency)
            pa0 = *(const float4*)(Ag + k0 + BK);
            pa1 = *(const float4*)(Ag + k0 + BK + 4);
            pb0 = *(const float4*)(Bg + k0 + BK);
            pb1 = *(const float4*)(Bg + k0 + BK + 4);
        }
        bf16x8 a_h[2], a_l[2], b_h[2], b_l[2];
        #pragma unroll
        for (int fm = 0; fm < 2; fm++) {       // wave reads contiguous 1KB: conflict-free
            a_h[fm] = *(const bf16x8*)&As_h[(wr * 32 + fm * 16 + fr) * BK + kg];
            a_l[fm] = *(const bf16x8*)&As_l[(wr * 32 + fm * 16 + fr) * BK + kg];
        }
        #pragma unroll
        for (int fn = 0; fn < 2; fn++) {
            b_h[fn] = *(const bf16x8*)&Bs_h[(wc * 32 + fn * 16 + fr) * BK + kg];
            b_l[fn] = *(const bf16x8*)&Bs_l[(wc * 32 + fn * 16 + fr) * BK + kg];
        }
        #pragma unroll
        for (int fm = 0; fm < 2; fm++)
            #pragma unroll
            for (int fn = 0; fn < 2; fn++) {
                acc[fm][fn] = __builtin_amdgcn_mfma_f32_16x16x32_bf16(a_h[fm], b_h[fn], acc[fm][fn], 0, 0, 0);
                acc[fm][fn] = __builtin_amdgcn_mfma_f32_16x16x32_bf16(a_h[fm], b_l[fn], acc[fm][fn], 0, 0, 0);
                acc[fm][fn] = __builtin_amdgcn_mfma_f32_16x16x32_bf16(a_l[fm], b_h[fn], acc[fm][fn], 0, 0, 0);
            }
    }

    // epilogue: C/D layout col=lane&15, row=(lane>>4)*4+reg  [guide m89-verified]
    #pragma unroll
    for (int fm = 0; fm < 2; fm++) {
        const int r0 = rowBase + wr * 32 + fm * 16 + (l >> 4) * 4;
        #pragma unroll
        for (int fn = 0; fn < 2; fn++) {
            const int c0 = colBase + wc * 32 + fn * 16 + (l & 15);
            #pragma unroll
            for (int r = 0; r < 4; r++) {
                float v = acc[fm][fn][r];
                const int rr = r0 + r;
                if (biasMode == 1) v += bias[c0];
                else if (biasMode == 2) v += bias[rr];
                if (gelu_flag) v = 0.5f * v * (1.0f + erff(v * 0.70710678118654752f));
                if (res) v += res[(size_t)rr * ldr + c0];
                C[(size_t)rr * ldc + c0] = v;
            }
        }
    }
}

__global__ __launch_bounds__(256)
void k_mgemm(const float* __restrict__ A, int lda, const float* __restrict__ B, int ldb,
             float* __restrict__ C, int ldc, int K,
             const float* __restrict__ bias, int biasMode,
             const float* __restrict__ res, int ldr, int gelu_flag) {
    mgemm_body(A, lda, B, ldb, C, ldc, K, bias, biasMode, res, ldr, gelu_flag);
}

// Q and K projections for head h in one launch (z selects).
__global__ __launch_bounds__(256)
void k_qkproj(const float* __restrict__ xln,
              const float* __restrict__ WqT, const float* __restrict__ WkT,
              const float* __restrict__ bq, const float* __restrict__ bk,
              float* __restrict__ Qh, float* __restrict__ Kh, int h) {
    if (blockIdx.z == 0)
        mgemm_body(xln, DIM, WqT + (size_t)h * DIM * DIM, DIM, Qh, DIM, DIM,
                   bq + h * DIM, 1, nullptr, 0, 0);
    else
        mgemm_body(xln, DIM, WkT + (size_t)h * DIM * DIM, DIM, Kh, DIM, DIM,
                   bk + h * DIM, 1, nullptr, 0, 0);
}

// ---------------------------------------------------------------------------
// 32x32 tiled fp32 transpose: dst[C][R] = src[R][C]^T
// ---------------------------------------------------------------------------
__device__ __forceinline__
void transpose_body(const float* __restrict__ src, float* __restrict__ dst, int R, int C) {
    __shared__ float tile[32][33];
    const int t = threadIdx.x;
    const int tx = t & 31, ty = t >> 5;
    const int x0 = blockIdx.x * 32, y0 = blockIdx.y * 32;
    #pragma unroll
    for (int i = 0; i < 4; i++)
        tile[ty + 8 * i][tx] = src[(size_t)(y0 + ty + 8 * i) * C + x0 + tx];
    __syncthreads();
    #pragma unroll
    for (int i = 0; i < 4; i++)
        dst[(size_t)(x0 + ty + 8 * i) * R + y0 + tx] = tile[tx][ty + 8 * i];
}

__global__ __launch_bounds__(256)
void k_transpose(const float* __restrict__ src, float* __restrict__ dst, int R, int C) {
    transpose_body(src, dst, R, C);
}

// Batched transpose of Wq/Wk/Wv: z = w*8 + h, each 512x512.
__global__ __launch_bounds__(256)
void k_transpose_qkv(const float* __restrict__ Wq, const float* __restrict__ Wk,
                     const float* __restrict__ Wv,
                     float* __restrict__ WqT, float* __restrict__ WkT,
                     float* __restrict__ WvT) {
    const int z = blockIdx.z;
    const int w = z >> 3, h = z & 7;
    const float* src = (w == 0 ? Wq : w == 1 ? Wk : Wv) + (size_t)h * DIM * DIM;
    float* dst       = (w == 0 ? WqT : w == 1 ? WkT : WvT) + (size_t)h * DIM * DIM;
    transpose_body(src, dst, DIM, DIM);
}

// ---------------------------------------------------------------------------
// In-place: S[i][j] = softmax_j( S[i][j]*scale + b[i][j] + c_h(i,j) )
// ---------------------------------------------------------------------------
__global__ __launch_bounds__(256)
void bias_softmax(float* __restrict__ S, const float* __restrict__ b,
                  const int* __restrict__ path_idx,
                  const int* __restrict__ path_len,
                  const float* __restrict__ d, int h) {
    const int i = blockIdx.x;
    const int t = threadIdx.x;
    const float scale = 0.04419417382415922f; // 1/sqrt(512)
    const int lane = t & 63, wid = t >> 6;
    __shared__ float redm[4];
    __shared__ float reds[4];

    float v[8];
    float m = -1e30f;
    #pragma unroll
    for (int k = 0; k < 8; k++) {
        const int j = t + k * 256;
        const size_t idx = (size_t)i * N_NODES + j;
        float val = S[idx] * scale + b[idx];
        const int len = path_len[idx];
        if (len > 0) {
            const int4 pi = ((const int4*)path_idx)[idx];
            float csum = d[(size_t)pi.x * 32 + h * 4 + 0];
            if (len > 1) csum += d[(size_t)pi.y * 32 + h * 4 + 1];
            if (len > 2) csum += d[(size_t)pi.z * 32 + h * 4 + 2];
            if (len > 3) csum += d[(size_t)pi.w * 32 + h * 4 + 3];
            val += csum / (float)len;
        }
        v[k] = val;
        m = fmaxf(m, val);
    }
    #pragma unroll
    for (int o = 32; o > 0; o >>= 1) m = fmaxf(m, __shfl_xor(m, o));
    if (lane == 0) redm[wid] = m;
    __syncthreads();
    m = fmaxf(fmaxf(redm[0], redm[1]), fmaxf(redm[2], redm[3]));

    float s = 0.0f;
    #pragma unroll
    for (int k = 0; k < 8; k++) { v[k] = expf(v[k] - m); s += v[k]; }
    #pragma unroll
    for (int o = 32; o > 0; o >>= 1) s += __shfl_xor(s, o);
    if (lane == 0) reds[wid] = s;
    __syncthreads();
    s = reds[0] + reds[1] + reds[2] + reds[3];
    const float inv = 1.0f / s;
    #pragma unroll
    for (int k = 0; k < 8; k++)
        S[(size_t)i * N_NODES + t + k * 256] = v[k] * inv;
}

// ---------------------------------------------------------------------------
extern "C" void kernel_launch(void* const* d_in, const int* in_sizes, int n_in,
                              void* d_out, int out_size, void* d_ws, size_t ws_size,
                              hipStream_t stream) {
    const float* x         = (const float*)d_in[0];
    const float* edge_attr = (const float*)d_in[1];
    const float* b         = (const float*)d_in[2];
    const int*   path_idx  = (const int*)d_in[3];
    const int*   path_len  = (const int*)d_in[4];
    const float* Wq = (const float*)d_in[5];  const float* bq = (const float*)d_in[6];
    const float* Wk = (const float*)d_in[7];  const float* bk = (const float*)d_in[8];
    const float* Wv = (const float*)d_in[9];  const float* bv = (const float*)d_in[10];
    const float* edge_vec = (const float*)d_in[11];
    const float* Wo = (const float*)d_in[12]; const float* bo = (const float*)d_in[13];
    const float* ln1g = (const float*)d_in[14]; const float* ln1b = (const float*)d_in[15];
    const float* ln2g = (const float*)d_in[16]; const float* ln2b = (const float*)d_in[17];
    const float* W1 = (const float*)d_in[18]; const float* b1 = (const float*)d_in[19];
    const float* W2 = (const float*)d_in[20]; const float* b2 = (const float*)d_in[21];
    float* out = (float*)d_out;

    // workspace layout (floats), 104.9 MB total (<=107MB known-good)
    float* ws = (float*)d_ws;
    float* xln  = ws;                    // 1M floats
    float* wt   = ws + 1048576;          // 6.29M: WqT/WkT/WvT; later WoT/W1T/W2T
    float* WqT  = wt;
    float* WkT  = wt + 2097152;
    float* WvT  = wt + 4194304;
    float* WoT  = wt;                    // overlay after attention
    float* W1T  = wt + 2097152;
    float* W2T  = wt + 3145728;
    float* dbuf = ws + 7340032;          // 1M
    float* Qh   = ws + 8388608;          // 1M
    float* Kh   = ws + 9437184;          // 1M
    float* VTh  = ws + 10485760;         // 1M  (V^T for head h: [D][N])
    float* S    = ws + 11534336;         // 4.19M (later ffmid)
    float* ffmid= S;
    float* mh   = ws + 15728640;         // 8.39M [N][H*D]
    float* x1   = ws + 24117248;         // 1M
    float* h2   = ws + 25165824;         // 1M
    (void)ws_size; (void)in_sizes; (void)n_in; (void)out_size;

    // 1) LN1 ; 2) edge dot table ; 3) transpose Wq/Wk/Wv -> [e][d]
    ln_kernel<<<N_NODES, 256, 0, stream>>>(x, ln1g, ln1b, xln);
    edge_d_kernel<<<NEDGE / 256, 256, 0, stream>>>(edge_attr, edge_vec, dbuf);
    k_transpose_qkv<<<dim3(16, 16, 24), 256, 0, stream>>>(Wq, Wk, Wv, WqT, WkT, WvT);

    // 4) per-head attention
    for (int h = 0; h < HEADS; h++) {
        // Q,K: [N,D] = xln @ W^T ; V^T: [D,N] = WvT @ xln^T (NT form, bias on rows)
        k_qkproj<<<dim3(N_NODES / BM, DIM / BN, 2), 256, 0, stream>>>(
            xln, WqT, WkT, bq, bk, Qh, Kh, h);
        k_mgemm<<<dim3(DIM / BM, N_NODES / BN), 256, 0, stream>>>(
            WvT + (size_t)h * DIM * DIM, DIM, xln, DIM, VTh, N_NODES, DIM,
            bv + h * DIM, 2, nullptr, 0, 0);
        // S = Q @ K^T (raw logits; scale/bias in softmax)
        k_mgemm<<<dim3(N_NODES / BM, N_NODES / BN), 256, 0, stream>>>(
            Qh, DIM, Kh, DIM, S, N_NODES, DIM, nullptr, 0, nullptr, 0, 0);
        bias_softmax<<<N_NODES, 256, 0, stream>>>(S, b, path_idx, path_len, dbuf, h);
        // O_h = S @ V  (B = V^T in NT form), into concatenated mh
        k_mgemm<<<dim3(N_NODES / BM, DIM / BN), 256, 0, stream>>>(
            S, N_NODES, VTh, N_NODES, mh + (size_t)h * DIM, HEADS * DIM, N_NODES,
            nullptr, 0, nullptr, 0, 0);
    }

    // 5) transpose Wo/W1/W2 (overlays WqT region — safe after attention)
    k_transpose<<<dim3(16, 128), 256, 0, stream>>>(Wo, WoT, HEADS * DIM, DIM);
    k_transpose<<<dim3(64, 16),  256, 0, stream>>>(W1, W1T, DIM, FFDIM);
    k_transpose<<<dim3(16, 64),  256, 0, stream>>>(W2, W2T, FFDIM, DIM);

    // 6) x1 = mh @ Wo + bo + x
    k_mgemm<<<dim3(N_NODES / BM, DIM / BN), 256, 0, stream>>>(
        mh, HEADS * DIM, WoT, HEADS * DIM, x1, DIM, HEADS * DIM, bo, 1, x, DIM, 0);
    // 7) LN2
    ln_kernel<<<N_NODES, 256, 0, stream>>>(x1, ln2g, ln2b, h2);
    // 8) ffmid = gelu(h2 @ W1 + b1)
    k_mgemm<<<dim3(N_NODES / BM, FFDIM / BN), 256, 0, stream>>>(
        h2, DIM, W1T, DIM, ffmid, FFDIM, DIM, b1, 1, nullptr, 0, 1);
    // 9) out = ffmid @ W2 + b2 + x1
    k_mgemm<<<dim3(N_NODES / BM, DIM / BN), 256, 0, stream>>>(
        ffmid, FFDIM, W2T, FFDIM, out, DIM, FFDIM, b2, 1, x1, DIM, 0);
}

// Round 4
// 1405.430 us; speedup vs baseline: 2.3629x; 1.1813x over previous
//
#include <hip/hip_runtime.h>
#include <math.h>

#define N_NODES 2048
#define DIM     512
#define HEADS   8
#define FFDIM   2048
#define EDIM    64
#define PMAX    4
#define NEDGE   32768
#define NN      ((size_t)N_NODES * N_NODES)

// MFMA GEMM tile
#define BM 64
#define BN 64
#define BK 32

typedef __attribute__((ext_vector_type(8))) short bf16x8;           // MFMA A/B frag (8 bf16)
typedef __attribute__((ext_vector_type(8))) unsigned short u16x8;   // staging pack
typedef __attribute__((ext_vector_type(4))) float f32x4;            // MFMA acc

// ---------------------------------------------------------------------------
// LayerNorm: one block (256 threads) per row of 512 floats.
// ---------------------------------------------------------------------------
__global__ __launch_bounds__(256)
void ln_kernel(const float* __restrict__ x, const float* __restrict__ g,
               const float* __restrict__ beta, float* __restrict__ out) {
    const int row = blockIdx.x;
    const int t = threadIdx.x;
    const float* xr = x + (size_t)row * DIM;
    const float v0 = xr[t];
    const float v1 = xr[t + 256];
    __shared__ float red[4];
    const int lane = t & 63, wid = t >> 6;

    float s = v0 + v1;
    #pragma unroll
    for (int o = 32; o > 0; o >>= 1) s += __shfl_xor(s, o);
    if (lane == 0) red[wid] = s;
    __syncthreads();
    const float mu = (red[0] + red[1] + red[2] + red[3]) * (1.0f / DIM);
    __syncthreads();

    const float d0 = v0 - mu, d1 = v1 - mu;
    float vs = d0 * d0 + d1 * d1;
    #pragma unroll
    for (int o = 32; o > 0; o >>= 1) vs += __shfl_xor(vs, o);
    if (lane == 0) red[wid] = vs;
    __syncthreads();
    const float var = (red[0] + red[1] + red[2] + red[3]) * (1.0f / DIM);
    const float inv = 1.0f / sqrtf(var + 1e-5f);

    out[(size_t)row * DIM + t]       = d0 * inv * g[t] + beta[t];
    out[(size_t)row * DIM + t + 256] = d1 * inv * g[t + 256] + beta[t + 256];
}

// ---------------------------------------------------------------------------
// d2[e][p][h] = sum_f edge_attr[e][f] * edge_vec[h][p][f]   (layout [E][P][H])
// (p-major-then-h so one float4 fetches 4 heads of a head-group)
// ---------------------------------------------------------------------------
__global__ __launch_bounds__(256)
void edge_d_kernel(const float* __restrict__ edge_attr,
                   const float* __restrict__ edge_vec,
                   float* __restrict__ dout) {
    __shared__ float ev[HEADS * PMAX * EDIM]; // 2048 floats
    const int t = threadIdx.x;
    for (int i = t; i < HEADS * PMAX * EDIM; i += 256) ev[i] = edge_vec[i];
    __syncthreads();

    const int e = blockIdx.x * 256 + t;
    float acc[32];
    #pragma unroll
    for (int i = 0; i < 32; i++) acc[i] = 0.0f;

    const float4* ea = (const float4*)(edge_attr + (size_t)e * EDIM);
    #pragma unroll
    for (int f4 = 0; f4 < EDIM / 4; f4++) {
        const float4 a = ea[f4];
        #pragma unroll
        for (int hp = 0; hp < 32; hp++) {   // hp = h*4+p
            const float4 v = ((const float4*)(ev + hp * EDIM))[f4];
            acc[hp] += a.x * v.x + a.y * v.y + a.z * v.z + a.w * v.w;
        }
    }
    float* o = dout + (size_t)e * 32;
    #pragma unroll
    for (int hp = 0; hp < 32; hp++)
        o[(hp & 3) * 8 + (hp >> 2)] = acc[hp];   // [p][h]
}

// ---------------------------------------------------------------------------
// Spatial-bias precompute for a 4-head group hg (heads hg*4..hg*4+3):
// cb[hh][i][j] = b[i][j] + (len>0 ? sum_p d2[e_p][p][hg*4+hh] / len : 0)
// Reads path data ONCE per group instead of once per head.
// ---------------------------------------------------------------------------
__global__ __launch_bounds__(256)
void k_spatial_bias(const float* __restrict__ b,
                    const int* __restrict__ path_idx,
                    const int* __restrict__ path_len,
                    const float* __restrict__ d2,
                    float* __restrict__ cb, int hg) {
    const size_t idx = (size_t)blockIdx.x * 256 + threadIdx.x;   // flat over N*N
    const int len = path_len[idx];
    const float bb = b[idx];
    float c0 = 0.f, c1 = 0.f, c2 = 0.f, c3 = 0.f;
    if (len > 0) {
        const int4 pi = ((const int4*)path_idx)[idx];
        const float4 v0 = *(const float4*)(d2 + (size_t)pi.x * 32 + 0 * 8 + hg * 4);
        c0 = v0.x; c1 = v0.y; c2 = v0.z; c3 = v0.w;
        if (len > 1) {
            const float4 v1 = *(const float4*)(d2 + (size_t)pi.y * 32 + 1 * 8 + hg * 4);
            c0 += v1.x; c1 += v1.y; c2 += v1.z; c3 += v1.w;
        }
        if (len > 2) {
            const float4 v2 = *(const float4*)(d2 + (size_t)pi.z * 32 + 2 * 8 + hg * 4);
            c0 += v2.x; c1 += v2.y; c2 += v2.z; c3 += v2.w;
        }
        if (len > 3) {
            const float4 v3 = *(const float4*)(d2 + (size_t)pi.w * 32 + 3 * 8 + hg * 4);
            c0 += v3.x; c1 += v3.y; c2 += v3.z; c3 += v3.w;
        }
        const float inv = 1.0f / (float)len;
        c0 *= inv; c1 *= inv; c2 *= inv; c3 *= inv;
    }
    cb[0 * NN + idx] = bb + c0;
    cb[1 * NN + idx] = bb + c1;
    cb[2 * NN + idx] = bb + c2;
    cb[3 * NN + idx] = bb + c3;
}

// ---------------------------------------------------------------------------
// fp32 -> (bf16 hi, bf16 lo) split, truncation-based (pure bit ops + 1 sub).
// ---------------------------------------------------------------------------
__device__ __forceinline__ void cvt8(float4 a, float4 b, u16x8* hi, u16x8* lo) {
    float v[8] = {a.x, a.y, a.z, a.w, b.x, b.y, b.z, b.w};
    u16x8 h, l;
    #pragma unroll
    for (int i = 0; i < 8; i++) {
        const unsigned int u = __float_as_uint(v[i]);
        h[i] = (unsigned short)(u >> 16);
        const float r = v[i] - __uint_as_float(u & 0xFFFF0000u);
        l[i] = (unsigned short)(__float_as_uint(r) >> 16);
    }
    *hi = h; *lo = l;
}

// ---------------------------------------------------------------------------
// bf16x3 MFMA GEMM (NT): C[M][N] = alpha * (A[M][K] * B[N][K]^T) [+bias][+res]
// biasMode: 0 none, 1 bias[col], 2 bias[row].
// ---------------------------------------------------------------------------
__device__ __forceinline__
void mgemm_body(const float* __restrict__ A, int lda,
                const float* __restrict__ B, int ldb,
                float* __restrict__ C, int ldc, int K, float alpha,
                const float* __restrict__ bias, int biasMode,
                const float* __restrict__ res, int ldr, int gelu_flag) {
    __shared__ __attribute__((aligned(16))) unsigned short As_h[BM * BK];
    __shared__ __attribute__((aligned(16))) unsigned short As_l[BM * BK];
    __shared__ __attribute__((aligned(16))) unsigned short Bs_h[BN * BK];
    __shared__ __attribute__((aligned(16))) unsigned short Bs_l[BN * BK];

    const int t = threadIdx.x;
    const int l = t & 63;
    const int wave = t >> 6;
    const int wr = wave >> 1, wc = wave & 1;        // 2x2 wave grid
    const int rowBase = blockIdx.x * BM, colBase = blockIdx.y * BN;

    const int sRow = t >> 2, sCol = (t & 3) * 8;
    const float* Ag = A + (size_t)(rowBase + sRow) * lda + sCol;
    const float* Bg = B + (size_t)(colBase + sRow) * ldb + sCol;

    f32x4 acc[2][2] = {};

    float4 pa0 = *(const float4*)(Ag);
    float4 pa1 = *(const float4*)(Ag + 4);
    float4 pb0 = *(const float4*)(Bg);
    float4 pb1 = *(const float4*)(Bg + 4);

    const int fr = l & 15;
    const int kg = (l >> 4) * 8;

    for (int k0 = 0; k0 < K; k0 += BK) {
        u16x8 ah, al, bh, bl;
        cvt8(pa0, pa1, &ah, &al);
        cvt8(pb0, pb1, &bh, &bl);
        __syncthreads();
        *(u16x8*)&As_h[sRow * BK + sCol] = ah;
        *(u16x8*)&As_l[sRow * BK + sCol] = al;
        *(u16x8*)&Bs_h[sRow * BK + sCol] = bh;
        *(u16x8*)&Bs_l[sRow * BK + sCol] = bl;
        __syncthreads();
        if (k0 + BK < K) {
            pa0 = *(const float4*)(Ag + k0 + BK);
            pa1 = *(const float4*)(Ag + k0 + BK + 4);
            pb0 = *(const float4*)(Bg + k0 + BK);
            pb1 = *(const float4*)(Bg + k0 + BK + 4);
        }
        bf16x8 a_h[2], a_l[2], b_h[2], b_l[2];
        #pragma unroll
        for (int fm = 0; fm < 2; fm++) {
            a_h[fm] = *(const bf16x8*)&As_h[(wr * 32 + fm * 16 + fr) * BK + kg];
            a_l[fm] = *(const bf16x8*)&As_l[(wr * 32 + fm * 16 + fr) * BK + kg];
        }
        #pragma unroll
        for (int fn = 0; fn < 2; fn++) {
            b_h[fn] = *(const bf16x8*)&Bs_h[(wc * 32 + fn * 16 + fr) * BK + kg];
            b_l[fn] = *(const bf16x8*)&Bs_l[(wc * 32 + fn * 16 + fr) * BK + kg];
        }
        #pragma unroll
        for (int fm = 0; fm < 2; fm++)
            #pragma unroll
            for (int fn = 0; fn < 2; fn++) {
                acc[fm][fn] = __builtin_amdgcn_mfma_f32_16x16x32_bf16(a_h[fm], b_h[fn], acc[fm][fn], 0, 0, 0);
                acc[fm][fn] = __builtin_amdgcn_mfma_f32_16x16x32_bf16(a_h[fm], b_l[fn], acc[fm][fn], 0, 0, 0);
                acc[fm][fn] = __builtin_amdgcn_mfma_f32_16x16x32_bf16(a_l[fm], b_h[fn], acc[fm][fn], 0, 0, 0);
            }
    }

    // epilogue: C/D layout col=lane&15, row=(lane>>4)*4+reg
    #pragma unroll
    for (int fm = 0; fm < 2; fm++) {
        const int r0 = rowBase + wr * 32 + fm * 16 + (l >> 4) * 4;
        #pragma unroll
        for (int fn = 0; fn < 2; fn++) {
            const int c0 = colBase + wc * 32 + fn * 16 + (l & 15);
            #pragma unroll
            for (int r = 0; r < 4; r++) {
                float v = acc[fm][fn][r] * alpha;
                const int rr = r0 + r;
                if (biasMode == 1) v += bias[c0];
                else if (biasMode == 2) v += bias[rr];
                if (gelu_flag) v = 0.5f * v * (1.0f + erff(v * 0.70710678118654752f));
                if (res) v += res[(size_t)rr * ldr + c0];
                C[(size_t)rr * ldc + c0] = v;
            }
        }
    }
}

__global__ __launch_bounds__(256)
void k_mgemm(const float* __restrict__ A, int lda, const float* __restrict__ B, int ldb,
             float* __restrict__ C, int ldc, int K, float alpha,
             const float* __restrict__ bias, int biasMode,
             const float* __restrict__ res, int ldr, int gelu_flag) {
    mgemm_body(A, lda, B, ldb, C, ldc, K, alpha, bias, biasMode, res, ldr, gelu_flag);
}

// Q and K projections for head h in one launch (z selects).
__global__ __launch_bounds__(256)
void k_qkproj(const float* __restrict__ xln,
              const float* __restrict__ WqT, const float* __restrict__ WkT,
              const float* __restrict__ bq, const float* __restrict__ bk,
              float* __restrict__ Qh, float* __restrict__ Kh, int h) {
    if (blockIdx.z == 0)
        mgemm_body(xln, DIM, WqT + (size_t)h * DIM * DIM, DIM, Qh, DIM, DIM, 1.0f,
                   bq + h * DIM, 1, nullptr, 0, 0);
    else
        mgemm_body(xln, DIM, WkT + (size_t)h * DIM * DIM, DIM, Kh, DIM, DIM, 1.0f,
                   bk + h * DIM, 1, nullptr, 0, 0);
}

// ---------------------------------------------------------------------------
// 32x32 tiled fp32 transpose: dst[C][R] = src[R][C]^T
// ---------------------------------------------------------------------------
__device__ __forceinline__
void transpose_body(const float* __restrict__ src, float* __restrict__ dst, int R, int C) {
    __shared__ float tile[32][33];
    const int t = threadIdx.x;
    const int tx = t & 31, ty = t >> 5;
    const int x0 = blockIdx.x * 32, y0 = blockIdx.y * 32;
    #pragma unroll
    for (int i = 0; i < 4; i++)
        tile[ty + 8 * i][tx] = src[(size_t)(y0 + ty + 8 * i) * C + x0 + tx];
    __syncthreads();
    #pragma unroll
    for (int i = 0; i < 4; i++)
        dst[(size_t)(x0 + ty + 8 * i) * R + y0 + tx] = tile[tx][ty + 8 * i];
}

__global__ __launch_bounds__(256)
void k_transpose(const float* __restrict__ src, float* __restrict__ dst, int R, int C) {
    transpose_body(src, dst, R, C);
}

__global__ __launch_bounds__(256)
void k_transpose_qkv(const float* __restrict__ Wq, const float* __restrict__ Wk,
                     const float* __restrict__ Wv,
                     float* __restrict__ WqT, float* __restrict__ WkT,
                     float* __restrict__ WvT) {
    const int z = blockIdx.z;
    const int w = z >> 3, h = z & 7;
    const float* src = (w == 0 ? Wq : w == 1 ? Wk : Wv) + (size_t)h * DIM * DIM;
    float* dst       = (w == 0 ? WqT : w == 1 ? WkT : WvT) + (size_t)h * DIM * DIM;
    transpose_body(src, dst, DIM, DIM);
}

// ---------------------------------------------------------------------------
// Plain in-place row softmax (bias already folded in by the QK^T epilogue).
// ---------------------------------------------------------------------------
__global__ __launch_bounds__(256)
void k_softmax(float* __restrict__ S) {
    const int i = blockIdx.x;
    const int t = threadIdx.x;
    const int lane = t & 63, wid = t >> 6;
    __shared__ float red[4];

    float v[8];
    float m = -1e30f;
    #pragma unroll
    for (int k = 0; k < 8; k++) {
        v[k] = S[(size_t)i * N_NODES + t + k * 256];
        m = fmaxf(m, v[k]);
    }
    #pragma unroll
    for (int o = 32; o > 0; o >>= 1) m = fmaxf(m, __shfl_xor(m, o));
    if (lane == 0) red[wid] = m;
    __syncthreads();
    m = fmaxf(fmaxf(red[0], red[1]), fmaxf(red[2], red[3]));
    __syncthreads();

    float s = 0.0f;
    #pragma unroll
    for (int k = 0; k < 8; k++) { v[k] = expf(v[k] - m); s += v[k]; }
    #pragma unroll
    for (int o = 32; o > 0; o >>= 1) s += __shfl_xor(s, o);
    if (lane == 0) red[wid] = s;
    __syncthreads();
    s = red[0] + red[1] + red[2] + red[3];
    const float inv = 1.0f / s;
    #pragma unroll
    for (int k = 0; k < 8; k++)
        S[(size_t)i * N_NODES + t + k * 256] = v[k] * inv;
}

// ---------------------------------------------------------------------------
// Fallback: per-head gather softmax (used only if ws too small for cb planes)
// ---------------------------------------------------------------------------
__global__ __launch_bounds__(256)
void bias_softmax(float* __restrict__ S, const float* __restrict__ b,
                  const int* __restrict__ path_idx,
                  const int* __restrict__ path_len,
                  const float* __restrict__ d2, int h) {
    const int i = blockIdx.x;
    const int t = threadIdx.x;
    const float scale = 0.04419417382415922f; // 1/sqrt(512)
    const int lane = t & 63, wid = t >> 6;
    __shared__ float redm[4];
    __shared__ float reds[4];

    float v[8];
    float m = -1e30f;
    #pragma unroll
    for (int k = 0; k < 8; k++) {
        const int j = t + k * 256;
        const size_t idx = (size_t)i * N_NODES + j;
        float val = S[idx] * scale + b[idx];
        const int len = path_len[idx];
        if (len > 0) {
            const int4 pi = ((const int4*)path_idx)[idx];
            float csum = d2[(size_t)pi.x * 32 + 0 * 8 + h];
            if (len > 1) csum += d2[(size_t)pi.y * 32 + 1 * 8 + h];
            if (len > 2) csum += d2[(size_t)pi.z * 32 + 2 * 8 + h];
            if (len > 3) csum += d2[(size_t)pi.w * 32 + 3 * 8 + h];
            val += csum / (float)len;
        }
        v[k] = val;
        m = fmaxf(m, val);
    }
    #pragma unroll
    for (int o = 32; o > 0; o >>= 1) m = fmaxf(m, __shfl_xor(m, o));
    if (lane == 0) redm[wid] = m;
    __syncthreads();
    m = fmaxf(fmaxf(redm[0], redm[1]), fmaxf(redm[2], redm[3]));

    float s = 0.0f;
    #pragma unroll
    for (int k = 0; k < 8; k++) { v[k] = expf(v[k] - m); s += v[k]; }
    #pragma unroll
    for (int o = 32; o > 0; o >>= 1) s += __shfl_xor(s, o);
    if (lane == 0) reds[wid] = s;
    __syncthreads();
    s = reds[0] + reds[1] + reds[2] + reds[3];
    const float inv = 1.0f / s;
    #pragma unroll
    for (int k = 0; k < 8; k++)
        S[(size_t)i * N_NODES + t + k * 256] = v[k] * inv;
}

// ---------------------------------------------------------------------------
extern "C" void kernel_launch(void* const* d_in, const int* in_sizes, int n_in,
                              void* d_out, int out_size, void* d_ws, size_t ws_size,
                              hipStream_t stream) {
    const float* x         = (const float*)d_in[0];
    const float* edge_attr = (const float*)d_in[1];
    const float* b         = (const float*)d_in[2];
    const int*   path_idx  = (const int*)d_in[3];
    const int*   path_len  = (const int*)d_in[4];
    const float* Wq = (const float*)d_in[5];  const float* bq = (const float*)d_in[6];
    const float* Wk = (const float*)d_in[7];  const float* bk = (const float*)d_in[8];
    const float* Wv = (const float*)d_in[9];  const float* bv = (const float*)d_in[10];
    const float* edge_vec = (const float*)d_in[11];
    const float* Wo = (const float*)d_in[12]; const float* bo = (const float*)d_in[13];
    const float* ln1g = (const float*)d_in[14]; const float* ln1b = (const float*)d_in[15];
    const float* ln2g = (const float*)d_in[16]; const float* ln2b = (const float*)d_in[17];
    const float* W1 = (const float*)d_in[18]; const float* b1 = (const float*)d_in[19];
    const float* W2 = (const float*)d_in[20]; const float* b2 = (const float*)d_in[21];
    float* out = (float*)d_out;

    // workspace layout (floats)
    float* ws = (float*)d_ws;
    float* xln  = ws;                    // 1M
    float* wt   = ws + 1048576;          // 6.29M: WqT/WkT/WvT; later WoT/W1T/W2T
    float* WqT  = wt;
    float* WkT  = wt + 2097152;
    float* WvT  = wt + 4194304;
    float* WoT  = wt;                    // overlay after attention
    float* W1T  = wt + 2097152;
    float* W2T  = wt + 3145728;
    float* dbuf = ws + 7340032;          // 1M
    float* Qh   = ws + 8388608;          // 1M
    float* Kh   = ws + 9437184;          // 1M
    float* VTh  = ws + 10485760;         // 1M  (V^T for head h: [D][N])
    float* S    = ws + 11534336;         // 4.19M (later ffmid)
    float* ffmid= S;
    float* mh   = ws + 15728640;         // 8.39M [N][H*D]
    float* x1   = ws + 24117248;         // 1M
    float* h2   = ws + 25165824;         // 1M
    float* cb   = ws + 26214400;         // 16.78M: 4 planes of (b + c_h), fast path only
    const int fastPath = (ws_size >= (size_t)(26214400 + 16777216) * 4);
    (void)in_sizes; (void)n_in; (void)out_size;

    const float scale = 0.04419417382415922f; // 1/sqrt(512)

    // 1) LN1 ; 2) edge dot table [E][P][H] ; 3) transpose Wq/Wk/Wv
    ln_kernel<<<N_NODES, 256, 0, stream>>>(x, ln1g, ln1b, xln);
    edge_d_kernel<<<NEDGE / 256, 256, 0, stream>>>(edge_attr, edge_vec, dbuf);
    k_transpose_qkv<<<dim3(16, 16, 24), 256, 0, stream>>>(Wq, Wk, Wv, WqT, WkT, WvT);

    // 4) per-head attention
    for (int h = 0; h < HEADS; h++) {
        if (fastPath && (h & 3) == 0)    // refresh 4-head bias planes per group
            k_spatial_bias<<<(int)(NN / 256), 256, 0, stream>>>(
                b, path_idx, path_len, dbuf, cb, h >> 2);

        k_qkproj<<<dim3(N_NODES / BM, DIM / BN, 2), 256, 0, stream>>>(
            xln, WqT, WkT, bq, bk, Qh, Kh, h);
        k_mgemm<<<dim3(DIM / BM, N_NODES / BN), 256, 0, stream>>>(
            WvT + (size_t)h * DIM * DIM, DIM, xln, DIM, VTh, N_NODES, DIM, 1.0f,
            bv + h * DIM, 2, nullptr, 0, 0);

        if (fastPath) {
            // S = scale*(Q K^T) + (b + c_h)  folded in epilogue
            k_mgemm<<<dim3(N_NODES / BM, N_NODES / BN), 256, 0, stream>>>(
                Qh, DIM, Kh, DIM, S, N_NODES, DIM, scale, nullptr, 0,
                cb + (size_t)(h & 3) * NN, N_NODES, 0);
            k_softmax<<<N_NODES, 256, 0, stream>>>(S);
        } else {
            k_mgemm<<<dim3(N_NODES / BM, N_NODES / BN), 256, 0, stream>>>(
                Qh, DIM, Kh, DIM, S, N_NODES, DIM, 1.0f, nullptr, 0, nullptr, 0, 0);
            bias_softmax<<<N_NODES, 256, 0, stream>>>(S, b, path_idx, path_len, dbuf, h);
        }

        // O_h = S @ V  (B = V^T in NT form), into concatenated mh
        k_mgemm<<<dim3(N_NODES / BM, DIM / BN), 256, 0, stream>>>(
            S, N_NODES, VTh, N_NODES, mh + (size_t)h * DIM, HEADS * DIM, N_NODES, 1.0f,
            nullptr, 0, nullptr, 0, 0);
    }

    // 5) transpose Wo/W1/W2 (overlays WqT region — safe after attention)
    k_transpose<<<dim3(16, 128), 256, 0, stream>>>(Wo, WoT, HEADS * DIM, DIM);
    k_transpose<<<dim3(64, 16),  256, 0, stream>>>(W1, W1T, DIM, FFDIM);
    k_transpose<<<dim3(16, 64),  256, 0, stream>>>(W2, W2T, FFDIM, DIM);

    // 6) x1 = mh @ Wo + bo + x
    k_mgemm<<<dim3(N_NODES / BM, DIM / BN), 256, 0, stream>>>(
        mh, HEADS * DIM, WoT, HEADS * DIM, x1, DIM, HEADS * DIM, 1.0f, bo, 1, x, DIM, 0);
    // 7) LN2
    ln_kernel<<<N_NODES, 256, 0, stream>>>(x1, ln2g, ln2b, h2);
    // 8) ffmid = gelu(h2 @ W1 + b1)
    k_mgemm<<<dim3(N_NODES / BM, FFDIM / BN), 256, 0, stream>>>(
        h2, DIM, W1T, DIM, ffmid, FFDIM, DIM, 1.0f, b1, 1, nullptr, 0, 1);
    // 9) out = ffmid @ W2 + b2 + x1
    k_mgemm<<<dim3(N_NODES / BM, DIM / BN), 256, 0, stream>>>(
        ffmid, FFDIM, W2T, FFDIM, out, DIM, FFDIM, 1.0f, b2, 1, x1, DIM, 0);
}

// Round 5
// 1187.012 us; speedup vs baseline: 2.7977x; 1.1840x over previous
//
#include <hip/hip_runtime.h>
#include <math.h>

#define N_NODES 2048
#define DIM     512
#define HEADS   8
#define FFDIM   2048
#define EDIM    64
#define PMAX    4
#define NEDGE   32768
#define NN      ((size_t)N_NODES * N_NODES)

// MFMA GEMM tile
#define BM 64
#define BN 64
#define BK 32
#define BKP (BK + 8)   // +16B/row pad: quarter-wave b128 reads hit all 8 bank-quads

typedef __attribute__((ext_vector_type(8))) short bf16x8;           // MFMA A/B frag (8 bf16)
typedef __attribute__((ext_vector_type(8))) unsigned short u16x8;   // staging pack
typedef __attribute__((ext_vector_type(4))) float f32x4;            // MFMA acc

// ---------------------------------------------------------------------------
// LayerNorm: one block (256 threads) per row of 512 floats.
// ---------------------------------------------------------------------------
__global__ __launch_bounds__(256)
void ln_kernel(const float* __restrict__ x, const float* __restrict__ g,
               const float* __restrict__ beta, float* __restrict__ out) {
    const int row = blockIdx.x;
    const int t = threadIdx.x;
    const float* xr = x + (size_t)row * DIM;
    const float v0 = xr[t];
    const float v1 = xr[t + 256];
    __shared__ float red[4];
    const int lane = t & 63, wid = t >> 6;

    float s = v0 + v1;
    #pragma unroll
    for (int o = 32; o > 0; o >>= 1) s += __shfl_xor(s, o);
    if (lane == 0) red[wid] = s;
    __syncthreads();
    const float mu = (red[0] + red[1] + red[2] + red[3]) * (1.0f / DIM);
    __syncthreads();

    const float d0 = v0 - mu, d1 = v1 - mu;
    float vs = d0 * d0 + d1 * d1;
    #pragma unroll
    for (int o = 32; o > 0; o >>= 1) vs += __shfl_xor(vs, o);
    if (lane == 0) red[wid] = vs;
    __syncthreads();
    const float var = (red[0] + red[1] + red[2] + red[3]) * (1.0f / DIM);
    const float inv = 1.0f / sqrtf(var + 1e-5f);

    out[(size_t)row * DIM + t]       = d0 * inv * g[t] + beta[t];
    out[(size_t)row * DIM + t + 256] = d1 * inv * g[t + 256] + beta[t + 256];
}

// ---------------------------------------------------------------------------
// d2[e][p][h] = sum_f edge_attr[e][f] * edge_vec[h][p][f]   (layout [E][P][H])
// ---------------------------------------------------------------------------
__global__ __launch_bounds__(256)
void edge_d_kernel(const float* __restrict__ edge_attr,
                   const float* __restrict__ edge_vec,
                   float* __restrict__ dout) {
    __shared__ float ev[HEADS * PMAX * EDIM]; // 2048 floats
    const int t = threadIdx.x;
    for (int i = t; i < HEADS * PMAX * EDIM; i += 256) ev[i] = edge_vec[i];
    __syncthreads();

    const int e = blockIdx.x * 256 + t;
    float acc[32];
    #pragma unroll
    for (int i = 0; i < 32; i++) acc[i] = 0.0f;

    const float4* ea = (const float4*)(edge_attr + (size_t)e * EDIM);
    #pragma unroll
    for (int f4 = 0; f4 < EDIM / 4; f4++) {
        const float4 a = ea[f4];
        #pragma unroll
        for (int hp = 0; hp < 32; hp++) {   // hp = h*4+p
            const float4 v = ((const float4*)(ev + hp * EDIM))[f4];
            acc[hp] += a.x * v.x + a.y * v.y + a.z * v.z + a.w * v.w;
        }
    }
    float* o = dout + (size_t)e * 32;
    #pragma unroll
    for (int hp = 0; hp < 32; hp++)
        o[(hp & 3) * 8 + (hp >> 2)] = acc[hp];   // [p][h]
}

// ---------------------------------------------------------------------------
// Spatial-bias precompute for 4-head group hg:
// cb[hh][i][j] = b[i][j] + (len>0 ? sum_p d2[e_p][p][hg*4+hh] / len : 0)
// ---------------------------------------------------------------------------
__global__ __launch_bounds__(256)
void k_spatial_bias(const float* __restrict__ b,
                    const int* __restrict__ path_idx,
                    const int* __restrict__ path_len,
                    const float* __restrict__ d2,
                    float* __restrict__ cb, int hg) {
    const size_t idx = (size_t)blockIdx.x * 256 + threadIdx.x;   // flat over N*N
    const int len = path_len[idx];
    const float bb = b[idx];
    float c0 = 0.f, c1 = 0.f, c2 = 0.f, c3 = 0.f;
    if (len > 0) {
        const int4 pi = ((const int4*)path_idx)[idx];
        const float4 v0 = *(const float4*)(d2 + (size_t)pi.x * 32 + 0 * 8 + hg * 4);
        c0 = v0.x; c1 = v0.y; c2 = v0.z; c3 = v0.w;
        if (len > 1) {
            const float4 v1 = *(const float4*)(d2 + (size_t)pi.y * 32 + 1 * 8 + hg * 4);
            c0 += v1.x; c1 += v1.y; c2 += v1.z; c3 += v1.w;
        }
        if (len > 2) {
            const float4 v2 = *(const float4*)(d2 + (size_t)pi.z * 32 + 2 * 8 + hg * 4);
            c0 += v2.x; c1 += v2.y; c2 += v2.z; c3 += v2.w;
        }
        if (len > 3) {
            const float4 v3 = *(const float4*)(d2 + (size_t)pi.w * 32 + 3 * 8 + hg * 4);
            c0 += v3.x; c1 += v3.y; c2 += v3.z; c3 += v3.w;
        }
        const float inv = 1.0f / (float)len;
        c0 *= inv; c1 *= inv; c2 *= inv; c3 *= inv;
    }
    cb[0 * NN + idx] = bb + c0;
    cb[1 * NN + idx] = bb + c1;
    cb[2 * NN + idx] = bb + c2;
    cb[3 * NN + idx] = bb + c3;
}

// ---------------------------------------------------------------------------
// fp32 -> (bf16 hi, bf16 lo) split.
// ---------------------------------------------------------------------------
__device__ __forceinline__ void cvt8(float4 a, float4 b, u16x8* hi, u16x8* lo) {
    float v[8] = {a.x, a.y, a.z, a.w, b.x, b.y, b.z, b.w};
    u16x8 h, l;
    #pragma unroll
    for (int i = 0; i < 8; i++) {
        const unsigned int u = __float_as_uint(v[i]);
        h[i] = (unsigned short)(u >> 16);
        const float r = v[i] - __uint_as_float(u & 0xFFFF0000u);
        l[i] = (unsigned short)(__float_as_uint(r) >> 16);
    }
    *hi = h; *lo = l;
}

// ---------------------------------------------------------------------------
// bf16x3 MFMA GEMM (NT): C[M][N] = alpha*(A[M][K] B[N][K]^T) [+bias][+res]
// rb/cbase passed in so callers can remap blockIdx (swapped shapes, split-K).
// ---------------------------------------------------------------------------
__device__ __forceinline__
void mgemm_body(int rowBase, int colBase,
                const float* __restrict__ A, int lda,
                const float* __restrict__ B, int ldb,
                float* __restrict__ C, int ldc, int K, float alpha,
                const float* __restrict__ bias, int biasMode,
                const float* __restrict__ res, int ldr, int gelu_flag) {
    __shared__ __attribute__((aligned(16))) unsigned short As_h[BM * BKP];
    __shared__ __attribute__((aligned(16))) unsigned short As_l[BM * BKP];
    __shared__ __attribute__((aligned(16))) unsigned short Bs_h[BN * BKP];
    __shared__ __attribute__((aligned(16))) unsigned short Bs_l[BN * BKP];

    const int t = threadIdx.x;
    const int l = t & 63;
    const int wave = t >> 6;
    const int wr = wave >> 1, wc = wave & 1;        // 2x2 wave grid

    const int sRow = t >> 2, sCol = (t & 3) * 8;
    const float* Ag = A + (size_t)(rowBase + sRow) * lda + sCol;
    const float* Bg = B + (size_t)(colBase + sRow) * ldb + sCol;

    f32x4 acc[2][2] = {};

    float4 pa0 = *(const float4*)(Ag);
    float4 pa1 = *(const float4*)(Ag + 4);
    float4 pb0 = *(const float4*)(Bg);
    float4 pb1 = *(const float4*)(Bg + 4);

    const int fr = l & 15;
    const int kg = (l >> 4) * 8;

    for (int k0 = 0; k0 < K; k0 += BK) {
        u16x8 ah, al, bh, bl;
        cvt8(pa0, pa1, &ah, &al);
        cvt8(pb0, pb1, &bh, &bl);
        __syncthreads();
        *(u16x8*)&As_h[sRow * BKP + sCol] = ah;
        *(u16x8*)&As_l[sRow * BKP + sCol] = al;
        *(u16x8*)&Bs_h[sRow * BKP + sCol] = bh;
        *(u16x8*)&Bs_l[sRow * BKP + sCol] = bl;
        __syncthreads();
        if (k0 + BK < K) {
            pa0 = *(const float4*)(Ag + k0 + BK);
            pa1 = *(const float4*)(Ag + k0 + BK + 4);
            pb0 = *(const float4*)(Bg + k0 + BK);
            pb1 = *(const float4*)(Bg + k0 + BK + 4);
        }
        bf16x8 a_h[2], a_l[2], b_h[2], b_l[2];
        #pragma unroll
        for (int fm = 0; fm < 2; fm++) {
            a_h[fm] = *(const bf16x8*)&As_h[(wr * 32 + fm * 16 + fr) * BKP + kg];
            a_l[fm] = *(const bf16x8*)&As_l[(wr * 32 + fm * 16 + fr) * BKP + kg];
        }
        #pragma unroll
        for (int fn = 0; fn < 2; fn++) {
            b_h[fn] = *(const bf16x8*)&Bs_h[(wc * 32 + fn * 16 + fr) * BKP + kg];
            b_l[fn] = *(const bf16x8*)&Bs_l[(wc * 32 + fn * 16 + fr) * BKP + kg];
        }
        #pragma unroll
        for (int fm = 0; fm < 2; fm++)
            #pragma unroll
            for (int fn = 0; fn < 2; fn++) {
                acc[fm][fn] = __builtin_amdgcn_mfma_f32_16x16x32_bf16(a_h[fm], b_h[fn], acc[fm][fn], 0, 0, 0);
                acc[fm][fn] = __builtin_amdgcn_mfma_f32_16x16x32_bf16(a_h[fm], b_l[fn], acc[fm][fn], 0, 0, 0);
                acc[fm][fn] = __builtin_amdgcn_mfma_f32_16x16x32_bf16(a_l[fm], b_h[fn], acc[fm][fn], 0, 0, 0);
            }
    }

    // epilogue: C/D layout col=lane&15, row=(lane>>4)*4+reg
    #pragma unroll
    for (int fm = 0; fm < 2; fm++) {
        const int r0 = rowBase + wr * 32 + fm * 16 + (l >> 4) * 4;
        #pragma unroll
        for (int fn = 0; fn < 2; fn++) {
            const int c0 = colBase + wc * 32 + fn * 16 + (l & 15);
            #pragma unroll
            for (int r = 0; r < 4; r++) {
                float v = acc[fm][fn][r] * alpha;
                const int rr = r0 + r;
                if (biasMode == 1) v += bias[c0];
                else if (biasMode == 2) v += bias[rr];
                if (gelu_flag) v = 0.5f * v * (1.0f + erff(v * 0.70710678118654752f));
                if (res) v += res[(size_t)rr * ldr + c0];
                C[(size_t)rr * ldc + c0] = v;
            }
        }
    }
}

__global__ __launch_bounds__(256)
void k_mgemm(const float* __restrict__ A, int lda, const float* __restrict__ B, int ldb,
             float* __restrict__ C, int ldc, int K, float alpha,
             const float* __restrict__ bias, int biasMode,
             const float* __restrict__ res, int ldr, int gelu_flag) {
    mgemm_body(blockIdx.x * BM, blockIdx.y * BN,
               A, lda, B, ldb, C, ldc, K, alpha, bias, biasMode, res, ldr, gelu_flag);
}

// Q, K and V^T projections for head h in one launch: grid (32, 8, 3).
// z=0: Q[N,D], z=1: K[N,D] (x=M-block, y=N-block)
// z=2: V^T[D,N] = WvT_h @ xln^T (x=N-block, y=M-block; row bias)
__global__ __launch_bounds__(256)
void k_qkvproj(const float* __restrict__ xln,
               const float* __restrict__ WqT, const float* __restrict__ WkT,
               const float* __restrict__ WvT,
               const float* __restrict__ bq, const float* __restrict__ bk,
               const float* __restrict__ bv,
               float* __restrict__ Qh, float* __restrict__ Kh,
               float* __restrict__ VTh, int h) {
    const int z = blockIdx.z;
    if (z == 0)
        mgemm_body(blockIdx.x * BM, blockIdx.y * BN,
                   xln, DIM, WqT + (size_t)h * DIM * DIM, DIM, Qh, DIM, DIM, 1.0f,
                   bq + h * DIM, 1, nullptr, 0, 0);
    else if (z == 1)
        mgemm_body(blockIdx.x * BM, blockIdx.y * BN,
                   xln, DIM, WkT + (size_t)h * DIM * DIM, DIM, Kh, DIM, DIM, 1.0f,
                   bk + h * DIM, 1, nullptr, 0, 0);
    else
        mgemm_body(blockIdx.y * BM, blockIdx.x * BN,
                   WvT + (size_t)h * DIM * DIM, DIM, xln, DIM, VTh, N_NODES, DIM, 1.0f,
                   bv + h * DIM, 2, nullptr, 0, 0);
}

// PV with split-K=4: grid (32, 8, 4); partial z into part + z*(2048*512).
__global__ __launch_bounds__(256)
void k_pv_split(const float* __restrict__ S, const float* __restrict__ VTh,
                float* __restrict__ part) {
    const int z = blockIdx.z;
    mgemm_body(blockIdx.x * BM, blockIdx.y * BN,
               S + (size_t)z * 512, N_NODES, VTh + (size_t)z * 512, N_NODES,
               part + (size_t)z * N_NODES * DIM, DIM, 512, 1.0f,
               nullptr, 0, nullptr, 0, 0);
}

// Sum 4 split-K partials into mh (ldc = H*DIM). float4 per thread.
__global__ __launch_bounds__(256)
void k_pv_reduce(const float* __restrict__ part, float* __restrict__ mh_h) {
    const size_t q = (size_t)blockIdx.x * 256 + threadIdx.x;   // float4 index
    const size_t CH = (size_t)N_NODES * DIM / 4;               // chunk in float4s
    const float4 a0 = ((const float4*)part)[q];
    const float4 a1 = ((const float4*)part)[q + CH];
    const float4 a2 = ((const float4*)part)[q + 2 * CH];
    const float4 a3 = ((const float4*)part)[q + 3 * CH];
    float4 s;
    s.x = a0.x + a1.x + a2.x + a3.x;
    s.y = a0.y + a1.y + a2.y + a3.y;
    s.z = a0.z + a1.z + a2.z + a3.z;
    s.w = a0.w + a1.w + a2.w + a3.w;
    const size_t el = q * 4;
    const size_t r = el >> 9, c = el & 511;                    // [2048][512]
    *(float4*)&mh_h[r * (HEADS * DIM) + c] = s;
}

// ---------------------------------------------------------------------------
// 32x32 tiled fp32 transpose: dst[C][R] = src[R][C]^T
// ---------------------------------------------------------------------------
__device__ __forceinline__
void transpose_body(const float* __restrict__ src, float* __restrict__ dst, int R, int C) {
    __shared__ float tile[32][33];
    const int t = threadIdx.x;
    const int tx = t & 31, ty = t >> 5;
    const int x0 = blockIdx.x * 32, y0 = blockIdx.y * 32;
    #pragma unroll
    for (int i = 0; i < 4; i++)
        tile[ty + 8 * i][tx] = src[(size_t)(y0 + ty + 8 * i) * C + x0 + tx];
    __syncthreads();
    #pragma unroll
    for (int i = 0; i < 4; i++)
        dst[(size_t)(x0 + ty + 8 * i) * R + y0 + tx] = tile[tx][ty + 8 * i];
}

__global__ __launch_bounds__(256)
void k_transpose(const float* __restrict__ src, float* __restrict__ dst, int R, int C) {
    transpose_body(src, dst, R, C);
}

__global__ __launch_bounds__(256)
void k_transpose_qkv(const float* __restrict__ Wq, const float* __restrict__ Wk,
                     const float* __restrict__ Wv,
                     float* __restrict__ WqT, float* __restrict__ WkT,
                     float* __restrict__ WvT) {
    const int z = blockIdx.z;
    const int w = z >> 3, h = z & 7;
    const float* src = (w == 0 ? Wq : w == 1 ? Wk : Wv) + (size_t)h * DIM * DIM;
    float* dst       = (w == 0 ? WqT : w == 1 ? WkT : WvT) + (size_t)h * DIM * DIM;
    transpose_body(src, dst, DIM, DIM);
}

// ---------------------------------------------------------------------------
// Plain in-place row softmax (bias folded in by the QK^T epilogue).
// ---------------------------------------------------------------------------
__global__ __launch_bounds__(256)
void k_softmax(float* __restrict__ S) {
    const int i = blockIdx.x;
    const int t = threadIdx.x;
    const int lane = t & 63, wid = t >> 6;
    __shared__ float red[4];

    float v[8];
    float m = -1e30f;
    #pragma unroll
    for (int k = 0; k < 8; k++) {
        v[k] = S[(size_t)i * N_NODES + t + k * 256];
        m = fmaxf(m, v[k]);
    }
    #pragma unroll
    for (int o = 32; o > 0; o >>= 1) m = fmaxf(m, __shfl_xor(m, o));
    if (lane == 0) red[wid] = m;
    __syncthreads();
    m = fmaxf(fmaxf(red[0], red[1]), fmaxf(red[2], red[3]));
    __syncthreads();

    float s = 0.0f;
    #pragma unroll
    for (int k = 0; k < 8; k++) { v[k] = expf(v[k] - m); s += v[k]; }
    #pragma unroll
    for (int o = 32; o > 0; o >>= 1) s += __shfl_xor(s, o);
    if (lane == 0) red[wid] = s;
    __syncthreads();
    s = red[0] + red[1] + red[2] + red[3];
    const float inv = 1.0f / s;
    #pragma unroll
    for (int k = 0; k < 8; k++)
        S[(size_t)i * N_NODES + t + k * 256] = v[k] * inv;
}

// ---------------------------------------------------------------------------
// Fallback: per-head gather softmax (used only if ws too small for cb planes)
// ---------------------------------------------------------------------------
__global__ __launch_bounds__(256)
void bias_softmax(float* __restrict__ S, const float* __restrict__ b,
                  const int* __restrict__ path_idx,
                  const int* __restrict__ path_len,
                  const float* __restrict__ d2, int h) {
    const int i = blockIdx.x;
    const int t = threadIdx.x;
    const float scale = 0.04419417382415922f; // 1/sqrt(512)
    const int lane = t & 63, wid = t >> 6;
    __shared__ float redm[4];
    __shared__ float reds[4];

    float v[8];
    float m = -1e30f;
    #pragma unroll
    for (int k = 0; k < 8; k++) {
        const int j = t + k * 256;
        const size_t idx = (size_t)i * N_NODES + j;
        float val = S[idx] * scale + b[idx];
        const int len = path_len[idx];
        if (len > 0) {
            const int4 pi = ((const int4*)path_idx)[idx];
            float csum = d2[(size_t)pi.x * 32 + 0 * 8 + h];
            if (len > 1) csum += d2[(size_t)pi.y * 32 + 1 * 8 + h];
            if (len > 2) csum += d2[(size_t)pi.z * 32 + 2 * 8 + h];
            if (len > 3) csum += d2[(size_t)pi.w * 32 + 3 * 8 + h];
            val += csum / (float)len;
        }
        v[k] = val;
        m = fmaxf(m, val);
    }
    #pragma unroll
    for (int o = 32; o > 0; o >>= 1) m = fmaxf(m, __shfl_xor(m, o));
    if (lane == 0) redm[wid] = m;
    __syncthreads();
    m = fmaxf(fmaxf(redm[0], redm[1]), fmaxf(redm[2], redm[3]));

    float s = 0.0f;
    #pragma unroll
    for (int k = 0; k < 8; k++) { v[k] = expf(v[k] - m); s += v[k]; }
    #pragma unroll
    for (int o = 32; o > 0; o >>= 1) s += __shfl_xor(s, o);
    if (lane == 0) reds[wid] = s;
    __syncthreads();
    s = reds[0] + reds[1] + reds[2] + reds[3];
    const float inv = 1.0f / s;
    #pragma unroll
    for (int k = 0; k < 8; k++)
        S[(size_t)i * N_NODES + t + k * 256] = v[k] * inv;
}

// ---------------------------------------------------------------------------
extern "C" void kernel_launch(void* const* d_in, const int* in_sizes, int n_in,
                              void* d_out, int out_size, void* d_ws, size_t ws_size,
                              hipStream_t stream) {
    const float* x         = (const float*)d_in[0];
    const float* edge_attr = (const float*)d_in[1];
    const float* b         = (const float*)d_in[2];
    const int*   path_idx  = (const int*)d_in[3];
    const int*   path_len  = (const int*)d_in[4];
    const float* Wq = (const float*)d_in[5];  const float* bq = (const float*)d_in[6];
    const float* Wk = (const float*)d_in[7];  const float* bk = (const float*)d_in[8];
    const float* Wv = (const float*)d_in[9];  const float* bv = (const float*)d_in[10];
    const float* edge_vec = (const float*)d_in[11];
    const float* Wo = (const float*)d_in[12]; const float* bo = (const float*)d_in[13];
    const float* ln1g = (const float*)d_in[14]; const float* ln1b = (const float*)d_in[15];
    const float* ln2g = (const float*)d_in[16]; const float* ln2b = (const float*)d_in[17];
    const float* W1 = (const float*)d_in[18]; const float* b1 = (const float*)d_in[19];
    const float* W2 = (const float*)d_in[20]; const float* b2 = (const float*)d_in[21];
    float* out = (float*)d_out;

    // workspace layout (floats)
    float* ws = (float*)d_ws;
    float* xln  = ws;                    // 1M
    float* wt   = ws + 1048576;          // 6.29M: WqT/WkT/WvT; later WoT/W1T/W2T
    float* WqT  = wt;
    float* WkT  = wt + 2097152;
    float* WvT  = wt + 4194304;
    float* WoT  = wt;                    // overlay after attention
    float* W1T  = wt + 2097152;
    float* W2T  = wt + 3145728;
    float* dbuf = ws + 7340032;          // 1M
    float* Qh   = ws + 8388608;          // 1M
    float* Kh   = ws + 9437184;          // 1M
    float* VTh  = ws + 10485760;         // 1M  (V^T for head h: [D][N])
    float* S    = ws + 11534336;         // 4.19M (later ffmid)
    float* ffmid= S;
    float* mh   = ws + 15728640;         // 8.39M [N][H*D]
    float* x1   = ws + 24117248;         // 1M
    float* h2   = ws + 25165824;         // 1M
    float* cb   = ws + 26214400;         // 16.78M: 4 planes of (b + c_h)
    const int fastPath = (ws_size >= (size_t)(26214400 + 16777216) * 4);
    (void)in_sizes; (void)n_in; (void)out_size;

    const float scale = 0.04419417382415922f; // 1/sqrt(512)

    // 1) LN1 ; 2) edge dot table [E][P][H] ; 3) transpose Wq/Wk/Wv
    ln_kernel<<<N_NODES, 256, 0, stream>>>(x, ln1g, ln1b, xln);
    edge_d_kernel<<<NEDGE / 256, 256, 0, stream>>>(edge_attr, edge_vec, dbuf);
    k_transpose_qkv<<<dim3(16, 16, 24), 256, 0, stream>>>(Wq, Wk, Wv, WqT, WkT, WvT);

    // 4) per-head attention
    for (int h = 0; h < HEADS; h++) {
        if (fastPath && (h & 3) == 0)    // refresh 4-head bias planes per group
            k_spatial_bias<<<(int)(NN / 256), 256, 0, stream>>>(
                b, path_idx, path_len, dbuf, cb, h >> 2);

        k_qkvproj<<<dim3(N_NODES / BM, DIM / BN, 3), 256, 0, stream>>>(
            xln, WqT, WkT, WvT, bq, bk, bv, Qh, Kh, VTh, h);

        if (fastPath) {
            float* cbplane = cb + (size_t)(h & 3) * NN;
            // S = scale*(Q K^T) + (b + c_h)  folded in epilogue
            k_mgemm<<<dim3(N_NODES / BM, N_NODES / BN), 256, 0, stream>>>(
                Qh, DIM, Kh, DIM, S, N_NODES, DIM, scale, nullptr, 0,
                cbplane, N_NODES, 0);
            k_softmax<<<N_NODES, 256, 0, stream>>>(S);
            // PV split-K=4; partials overlay the consumed cb plane (h&3):
            // QK^T(h) has already read it, and the group's other planes are intact.
            k_pv_split<<<dim3(N_NODES / BM, DIM / BN, 4), 256, 0, stream>>>(S, VTh, cbplane);
            k_pv_reduce<<<(int)((size_t)N_NODES * DIM / 4 / 256), 256, 0, stream>>>(
                cbplane, mh + (size_t)h * DIM);
        } else {
            k_mgemm<<<dim3(N_NODES / BM, N_NODES / BN), 256, 0, stream>>>(
                Qh, DIM, Kh, DIM, S, N_NODES, DIM, 1.0f, nullptr, 0, nullptr, 0, 0);
            bias_softmax<<<N_NODES, 256, 0, stream>>>(S, b, path_idx, path_len, dbuf, h);
            k_mgemm<<<dim3(N_NODES / BM, DIM / BN), 256, 0, stream>>>(
                S, N_NODES, VTh, N_NODES, mh + (size_t)h * DIM, HEADS * DIM, N_NODES, 1.0f,
                nullptr, 0, nullptr, 0, 0);
        }
    }

    // 5) transpose Wo/W1/W2 (overlays WqT region — safe after attention)
    k_transpose<<<dim3(16, 128), 256, 0, stream>>>(Wo, WoT, HEADS * DIM, DIM);
    k_transpose<<<dim3(64, 16),  256, 0, stream>>>(W1, W1T, DIM, FFDIM);
    k_transpose<<<dim3(16, 64),  256, 0, stream>>>(W2, W2T, FFDIM, DIM);

    // 6) x1 = mh @ Wo + bo + x
    k_mgemm<<<dim3(N_NODES / BM, DIM / BN), 256, 0, stream>>>(
        mh, HEADS * DIM, WoT, HEADS * DIM, x1, DIM, HEADS * DIM, 1.0f, bo, 1, x, DIM, 0);
    // 7) LN2
    ln_kernel<<<N_NODES, 256, 0, stream>>>(x1, ln2g, ln2b, h2);
    // 8) ffmid = gelu(h2 @ W1 + b1)
    k_mgemm<<<dim3(N_NODES / BM, FFDIM / BN), 256, 0, stream>>>(
        h2, DIM, W1T, DIM, ffmid, FFDIM, DIM, 1.0f, b1, 1, nullptr, 0, 1);
    // 9) out = ffmid @ W2 + b2 + x1
    k_mgemm<<<dim3(N_NODES / BM, DIM / BN), 256, 0, stream>>>(
        ffmid, FFDIM, W2T, FFDIM, out, DIM, FFDIM, 1.0f, b2, 1, x1, DIM, 0);
}

// Round 6
// 1092.845 us; speedup vs baseline: 3.0388x; 1.0862x over previous
//
#include <hip/hip_runtime.h>
#include <math.h>

#define N_NODES 2048
#define DIM     512
#define HEADS   8
#define FFDIM   2048
#define EDIM    64
#define PMAX    4
#define NEDGE   32768
#define NN      ((size_t)N_NODES * N_NODES)

// MFMA GEMM tile: 128x128, 8 waves (512 threads) as 2x4, wave tile 64x32.
#define BM 128
#define BN 128
#define BK 32
#define BKP (BK + 8)   // 80B row stride: frag b128 reads land 2-way (free, m136)

typedef __attribute__((ext_vector_type(8))) short bf16x8;
typedef __attribute__((ext_vector_type(8))) unsigned short u16x8;
typedef __attribute__((ext_vector_type(4))) float f32x4;

__device__ __forceinline__ unsigned short f2bf_rne(float f) {
    unsigned int u = __float_as_uint(f);
    u += 0x7FFFu + ((u >> 16) & 1u);
    return (unsigned short)(u >> 16);
}
__device__ __forceinline__ float bf2f(unsigned short h) {
    return __uint_as_float((unsigned int)h << 16);
}

// ---------------------------------------------------------------------------
// LayerNorm: one block (256 threads) per row of 512 floats.
// ---------------------------------------------------------------------------
__global__ __launch_bounds__(256)
void ln_kernel(const float* __restrict__ x, const float* __restrict__ g,
               const float* __restrict__ beta, float* __restrict__ out) {
    const int row = blockIdx.x;
    const int t = threadIdx.x;
    const float* xr = x + (size_t)row * DIM;
    const float v0 = xr[t];
    const float v1 = xr[t + 256];
    __shared__ float red[4];
    const int lane = t & 63, wid = t >> 6;

    float s = v0 + v1;
    #pragma unroll
    for (int o = 32; o > 0; o >>= 1) s += __shfl_xor(s, o);
    if (lane == 0) red[wid] = s;
    __syncthreads();
    const float mu = (red[0] + red[1] + red[2] + red[3]) * (1.0f / DIM);
    __syncthreads();

    const float d0 = v0 - mu, d1 = v1 - mu;
    float vs = d0 * d0 + d1 * d1;
    #pragma unroll
    for (int o = 32; o > 0; o >>= 1) vs += __shfl_xor(vs, o);
    if (lane == 0) red[wid] = vs;
    __syncthreads();
    const float var = (red[0] + red[1] + red[2] + red[3]) * (1.0f / DIM);
    const float inv = 1.0f / sqrtf(var + 1e-5f);

    out[(size_t)row * DIM + t]       = d0 * inv * g[t] + beta[t];
    out[(size_t)row * DIM + t + 256] = d1 * inv * g[t + 256] + beta[t + 256];
}

// ---------------------------------------------------------------------------
// d2[e][p][h] = sum_f edge_attr[e][f] * edge_vec[h][p][f]   (layout [E][P][H])
// ---------------------------------------------------------------------------
__global__ __launch_bounds__(256)
void edge_d_kernel(const float* __restrict__ edge_attr,
                   const float* __restrict__ edge_vec,
                   float* __restrict__ dout) {
    __shared__ float ev[HEADS * PMAX * EDIM]; // 2048 floats
    const int t = threadIdx.x;
    for (int i = t; i < HEADS * PMAX * EDIM; i += 256) ev[i] = edge_vec[i];
    __syncthreads();

    const int e = blockIdx.x * 256 + t;
    float acc[32];
    #pragma unroll
    for (int i = 0; i < 32; i++) acc[i] = 0.0f;

    const float4* ea = (const float4*)(edge_attr + (size_t)e * EDIM);
    #pragma unroll
    for (int f4 = 0; f4 < EDIM / 4; f4++) {
        const float4 a = ea[f4];
        #pragma unroll
        for (int hp = 0; hp < 32; hp++) {   // hp = h*4+p
            const float4 v = ((const float4*)(ev + hp * EDIM))[f4];
            acc[hp] += a.x * v.x + a.y * v.y + a.z * v.z + a.w * v.w;
        }
    }
    float* o = dout + (size_t)e * 32;
    #pragma unroll
    for (int hp = 0; hp < 32; hp++)
        o[(hp & 3) * 8 + (hp >> 2)] = acc[hp];   // [p][h]
}

// ---------------------------------------------------------------------------
// Spatial-bias precompute for 4-head group hg, bf16 output planes:
// cb[hh][i][j] = bf16( b[i][j] + (len>0 ? sum_p d2[e_p][p][hg*4+hh]/len : 0) )
// ---------------------------------------------------------------------------
__global__ __launch_bounds__(256)
void k_spatial_bias(const float* __restrict__ b,
                    const int* __restrict__ path_idx,
                    const int* __restrict__ path_len,
                    const float* __restrict__ d2,
                    unsigned short* __restrict__ cb, int hg) {
    const size_t idx = (size_t)blockIdx.x * 256 + threadIdx.x;   // flat over N*N
    const int len = path_len[idx];
    const float bb = b[idx];
    float c0 = 0.f, c1 = 0.f, c2 = 0.f, c3 = 0.f;
    if (len > 0) {
        const int4 pi = ((const int4*)path_idx)[idx];
        const float4 v0 = *(const float4*)(d2 + (size_t)pi.x * 32 + 0 * 8 + hg * 4);
        c0 = v0.x; c1 = v0.y; c2 = v0.z; c3 = v0.w;
        if (len > 1) {
            const float4 v1 = *(const float4*)(d2 + (size_t)pi.y * 32 + 1 * 8 + hg * 4);
            c0 += v1.x; c1 += v1.y; c2 += v1.z; c3 += v1.w;
        }
        if (len > 2) {
            const float4 v2 = *(const float4*)(d2 + (size_t)pi.z * 32 + 2 * 8 + hg * 4);
            c0 += v2.x; c1 += v2.y; c2 += v2.z; c3 += v2.w;
        }
        if (len > 3) {
            const float4 v3 = *(const float4*)(d2 + (size_t)pi.w * 32 + 3 * 8 + hg * 4);
            c0 += v3.x; c1 += v3.y; c2 += v3.z; c3 += v3.w;
        }
        const float inv = 1.0f / (float)len;
        c0 *= inv; c1 *= inv; c2 *= inv; c3 *= inv;
    }
    cb[0 * NN + idx] = f2bf_rne(bb + c0);
    cb[1 * NN + idx] = f2bf_rne(bb + c1);
    cb[2 * NN + idx] = f2bf_rne(bb + c2);
    cb[3 * NN + idx] = f2bf_rne(bb + c3);
}

// ---------------------------------------------------------------------------
// fp32 -> (bf16 hi, bf16 lo) split, truncation-based.
// ---------------------------------------------------------------------------
__device__ __forceinline__ void cvt8(float4 a, float4 b, u16x8* hi, u16x8* lo) {
    float v[8] = {a.x, a.y, a.z, a.w, b.x, b.y, b.z, b.w};
    u16x8 h, l;
    #pragma unroll
    for (int i = 0; i < 8; i++) {
        const unsigned int u = __float_as_uint(v[i]);
        h[i] = (unsigned short)(u >> 16);
        const float r = v[i] - __uint_as_float(u & 0xFFFF0000u);
        l[i] = (unsigned short)(__float_as_uint(r) >> 16);
    }
    *hi = h; *lo = l;
}

// ---------------------------------------------------------------------------
// bf16x3 MFMA GEMM (NT): C[M][N] = alpha*(A[M][K] B[N][K]^T) [+bias][+res]
// 128x128 tile, 512 threads = 8 waves (2x4), wave tile 64x32 = 4x2 frags.
// 24 MFMA per K-step per wave (3 passes hh+hl+lh), reg-prefetched staging.
// biasMode: 0 none, 1 bias[col], 2 bias[row]. resF fp32 / resB bf16 residual.
// ---------------------------------------------------------------------------
__device__ __forceinline__
void mgemm_body(int rowBase, int colBase,
                const float* __restrict__ A, int lda,
                const float* __restrict__ B, int ldb,
                float* __restrict__ C, int ldc, int K, float alpha,
                const float* __restrict__ bias, int biasMode,
                const float* __restrict__ resF,
                const unsigned short* __restrict__ resB, int ldr, int gelu_flag) {
    __shared__ __attribute__((aligned(16))) unsigned short As_h[BM * BKP];
    __shared__ __attribute__((aligned(16))) unsigned short As_l[BM * BKP];
    __shared__ __attribute__((aligned(16))) unsigned short Bs_h[BN * BKP];
    __shared__ __attribute__((aligned(16))) unsigned short Bs_l[BN * BKP];

    const int t = threadIdx.x;        // 0..511
    const int l = t & 63;
    const int wave = t >> 6;          // 0..7
    const int wr = wave >> 2;         // 0..1 (row half)
    const int wc = wave & 3;          // 0..3 (col quarter)

    // staging: thread t loads 8 consecutive floats of row sRow (A and B tiles)
    const int sRow = t >> 2, sCol = (t & 3) * 8;
    const float* Ag = A + (size_t)(rowBase + sRow) * lda + sCol;
    const float* Bg = B + (size_t)(colBase + sRow) * ldb + sCol;

    f32x4 acc[4][2] = {};

    float4 pa0 = *(const float4*)(Ag);
    float4 pa1 = *(const float4*)(Ag + 4);
    float4 pb0 = *(const float4*)(Bg);
    float4 pb1 = *(const float4*)(Bg + 4);

    const int fr = l & 15;          // frag row within 16
    const int kg = (l >> 4) * 8;    // k-group start (elements)

    for (int k0 = 0; k0 < K; k0 += BK) {
        u16x8 ah, al, bh, bl;
        cvt8(pa0, pa1, &ah, &al);
        cvt8(pb0, pb1, &bh, &bl);
        __syncthreads();                       // prior frag reads done
        *(u16x8*)&As_h[sRow * BKP + sCol] = ah;
        *(u16x8*)&As_l[sRow * BKP + sCol] = al;
        *(u16x8*)&Bs_h[sRow * BKP + sCol] = bh;
        *(u16x8*)&Bs_l[sRow * BKP + sCol] = bl;
        __syncthreads();
        if (k0 + BK < K) {                     // prefetch next tiles
            pa0 = *(const float4*)(Ag + k0 + BK);
            pa1 = *(const float4*)(Ag + k0 + BK + 4);
            pb0 = *(const float4*)(Bg + k0 + BK);
            pb1 = *(const float4*)(Bg + k0 + BK + 4);
        }
        bf16x8 a_h[4], a_l[4], b_h[2], b_l[2];
        #pragma unroll
        for (int fm = 0; fm < 4; fm++) {
            const int r = (wr * 64 + fm * 16 + fr) * BKP + kg;
            a_h[fm] = *(const bf16x8*)&As_h[r];
            a_l[fm] = *(const bf16x8*)&As_l[r];
        }
        #pragma unroll
        for (int fn = 0; fn < 2; fn++) {
            const int r = (wc * 32 + fn * 16 + fr) * BKP + kg;
            b_h[fn] = *(const bf16x8*)&Bs_h[r];
            b_l[fn] = *(const bf16x8*)&Bs_l[r];
        }
        #pragma unroll
        for (int fm = 0; fm < 4; fm++)
            #pragma unroll
            for (int fn = 0; fn < 2; fn++) {
                acc[fm][fn] = __builtin_amdgcn_mfma_f32_16x16x32_bf16(a_h[fm], b_h[fn], acc[fm][fn], 0, 0, 0);
                acc[fm][fn] = __builtin_amdgcn_mfma_f32_16x16x32_bf16(a_h[fm], b_l[fn], acc[fm][fn], 0, 0, 0);
                acc[fm][fn] = __builtin_amdgcn_mfma_f32_16x16x32_bf16(a_l[fm], b_h[fn], acc[fm][fn], 0, 0, 0);
            }
    }

    // epilogue: C/D layout col=lane&15, row=(lane>>4)*4+reg  [m89-verified]
    #pragma unroll
    for (int fm = 0; fm < 4; fm++) {
        const int r0 = rowBase + wr * 64 + fm * 16 + (l >> 4) * 4;
        #pragma unroll
        for (int fn = 0; fn < 2; fn++) {
            const int c0 = colBase + wc * 32 + fn * 16 + (l & 15);
            #pragma unroll
            for (int r = 0; r < 4; r++) {
                float v = acc[fm][fn][r] * alpha;
                const int rr = r0 + r;
                if (biasMode == 1) v += bias[c0];
                else if (biasMode == 2) v += bias[rr];
                if (gelu_flag) v = 0.5f * v * (1.0f + erff(v * 0.70710678118654752f));
                if (resF) v += resF[(size_t)rr * ldr + c0];
                if (resB) v += bf2f(resB[(size_t)rr * ldr + c0]);
                C[(size_t)rr * ldc + c0] = v;
            }
        }
    }
}

__global__ __launch_bounds__(512, 2)
void k_mgemm(const float* __restrict__ A, int lda, const float* __restrict__ B, int ldb,
             float* __restrict__ C, int ldc, int K, float alpha,
             const float* __restrict__ bias, int biasMode,
             const float* __restrict__ resF,
             const unsigned short* __restrict__ resB, int ldr, int gelu_flag) {
    mgemm_body(blockIdx.x * BM, blockIdx.y * BN,
               A, lda, B, ldb, C, ldc, K, alpha, bias, biasMode, resF, resB, ldr, gelu_flag);
}

// Q, K and V^T projections for head h in one launch: grid (16, 4, 3).
__global__ __launch_bounds__(512, 2)
void k_qkvproj(const float* __restrict__ xln,
               const float* __restrict__ WqT, const float* __restrict__ WkT,
               const float* __restrict__ WvT,
               const float* __restrict__ bq, const float* __restrict__ bk,
               const float* __restrict__ bv,
               float* __restrict__ Qh, float* __restrict__ Kh,
               float* __restrict__ VTh, int h) {
    const int z = blockIdx.z;
    if (z == 0)
        mgemm_body(blockIdx.x * BM, blockIdx.y * BN,
                   xln, DIM, WqT + (size_t)h * DIM * DIM, DIM, Qh, DIM, DIM, 1.0f,
                   bq + h * DIM, 1, nullptr, nullptr, 0, 0);
    else if (z == 1)
        mgemm_body(blockIdx.x * BM, blockIdx.y * BN,
                   xln, DIM, WkT + (size_t)h * DIM * DIM, DIM, Kh, DIM, DIM, 1.0f,
                   bk + h * DIM, 1, nullptr, nullptr, 0, 0);
    else
        mgemm_body(blockIdx.y * BM, blockIdx.x * BN,   // M=512 side from y
                   WvT + (size_t)h * DIM * DIM, DIM, xln, DIM, VTh, N_NODES, DIM, 1.0f,
                   bv + h * DIM, 2, nullptr, nullptr, 0, 0);
}

// Split-K=4 GEMM into partial planes: grid (16, 4, 4).
// A,B advanced by z*Koff elements; partial z at part + z*(2048*512), ldc=512.
__global__ __launch_bounds__(512, 2)
void k_splitk(const float* __restrict__ A, int lda, const float* __restrict__ B, int ldb,
              float* __restrict__ part, int Kslice, int Koff) {
    const int z = blockIdx.z;
    mgemm_body(blockIdx.x * BM, blockIdx.y * BN,
               A + (size_t)z * Koff, lda, B + (size_t)z * Koff, ldb,
               part + (size_t)z * N_NODES * DIM, DIM, Kslice, 1.0f,
               nullptr, 0, nullptr, nullptr, 0, 0);
}

// Sum 4 partials + optional bias[col] + optional fp32 residual -> dst (ld dstLd).
__global__ __launch_bounds__(256)
void k_reduce4(const float* __restrict__ part, float* __restrict__ dst, int dstLd,
               const float* __restrict__ bias, const float* __restrict__ res, int resLd) {
    const size_t q = (size_t)blockIdx.x * 256 + threadIdx.x;   // float4 index
    const size_t CH = (size_t)N_NODES * DIM / 4;
    const float4 a0 = ((const float4*)part)[q];
    const float4 a1 = ((const float4*)part)[q + CH];
    const float4 a2 = ((const float4*)part)[q + 2 * CH];
    const float4 a3 = ((const float4*)part)[q + 3 * CH];
    float4 s;
    s.x = a0.x + a1.x + a2.x + a3.x;
    s.y = a0.y + a1.y + a2.y + a3.y;
    s.z = a0.z + a1.z + a2.z + a3.z;
    s.w = a0.w + a1.w + a2.w + a3.w;
    const size_t el = q * 4;
    const size_t r = el >> 9, c = el & 511;                    // [2048][512]
    if (bias) { s.x += bias[c]; s.y += bias[c + 1]; s.z += bias[c + 2]; s.w += bias[c + 3]; }
    if (res) {
        const float4 rv = *(const float4*)&res[r * resLd + c];
        s.x += rv.x; s.y += rv.y; s.z += rv.z; s.w += rv.w;
    }
    *(float4*)&dst[r * (size_t)dstLd + c] = s;
}

// ---------------------------------------------------------------------------
// 32x32 tiled fp32 transpose: dst[C][R] = src[R][C]^T
// ---------------------------------------------------------------------------
__device__ __forceinline__
void transpose_body(const float* __restrict__ src, float* __restrict__ dst, int R, int C) {
    __shared__ float tile[32][33];
    const int t = threadIdx.x;
    const int tx = t & 31, ty = t >> 5;
    const int x0 = blockIdx.x * 32, y0 = blockIdx.y * 32;
    #pragma unroll
    for (int i = 0; i < 4; i++)
        tile[ty + 8 * i][tx] = src[(size_t)(y0 + ty + 8 * i) * C + x0 + tx];
    __syncthreads();
    #pragma unroll
    for (int i = 0; i < 4; i++)
        dst[(size_t)(x0 + ty + 8 * i) * R + y0 + tx] = tile[tx][ty + 8 * i];
}

__global__ __launch_bounds__(256)
void k_transpose(const float* __restrict__ src, float* __restrict__ dst, int R, int C) {
    transpose_body(src, dst, R, C);
}

__global__ __launch_bounds__(256)
void k_transpose_qkv(const float* __restrict__ Wq, const float* __restrict__ Wk,
                     const float* __restrict__ Wv,
                     float* __restrict__ WqT, float* __restrict__ WkT,
                     float* __restrict__ WvT) {
    const int z = blockIdx.z;
    const int w = z >> 3, h = z & 7;
    const float* src = (w == 0 ? Wq : w == 1 ? Wk : Wv) + (size_t)h * DIM * DIM;
    float* dst       = (w == 0 ? WqT : w == 1 ? WkT : WvT) + (size_t)h * DIM * DIM;
    transpose_body(src, dst, DIM, DIM);
}

// ---------------------------------------------------------------------------
// Plain in-place row softmax (bias folded in by the QK^T epilogue).
// ---------------------------------------------------------------------------
__global__ __launch_bounds__(256)
void k_softmax(float* __restrict__ S) {
    const int i = blockIdx.x;
    const int t = threadIdx.x;
    const int lane = t & 63, wid = t >> 6;
    __shared__ float red[4];

    float v[8];
    float m = -1e30f;
    #pragma unroll
    for (int k = 0; k < 8; k++) {
        v[k] = S[(size_t)i * N_NODES + t + k * 256];
        m = fmaxf(m, v[k]);
    }
    #pragma unroll
    for (int o = 32; o > 0; o >>= 1) m = fmaxf(m, __shfl_xor(m, o));
    if (lane == 0) red[wid] = m;
    __syncthreads();
    m = fmaxf(fmaxf(red[0], red[1]), fmaxf(red[2], red[3]));
    __syncthreads();

    float s = 0.0f;
    #pragma unroll
    for (int k = 0; k < 8; k++) { v[k] = expf(v[k] - m); s += v[k]; }
    #pragma unroll
    for (int o = 32; o > 0; o >>= 1) s += __shfl_xor(s, o);
    if (lane == 0) red[wid] = s;
    __syncthreads();
    s = red[0] + red[1] + red[2] + red[3];
    const float inv = 1.0f / s;
    #pragma unroll
    for (int k = 0; k < 8; k++)
        S[(size_t)i * N_NODES + t + k * 256] = v[k] * inv;
}

// ---------------------------------------------------------------------------
extern "C" void kernel_launch(void* const* d_in, const int* in_sizes, int n_in,
                              void* d_out, int out_size, void* d_ws, size_t ws_size,
                              hipStream_t stream) {
    const float* x         = (const float*)d_in[0];
    const float* edge_attr = (const float*)d_in[1];
    const float* b         = (const float*)d_in[2];
    const int*   path_idx  = (const int*)d_in[3];
    const int*   path_len  = (const int*)d_in[4];
    const float* Wq = (const float*)d_in[5];  const float* bq = (const float*)d_in[6];
    const float* Wk = (const float*)d_in[7];  const float* bk = (const float*)d_in[8];
    const float* Wv = (const float*)d_in[9];  const float* bv = (const float*)d_in[10];
    const float* edge_vec = (const float*)d_in[11];
    const float* Wo = (const float*)d_in[12]; const float* bo = (const float*)d_in[13];
    const float* ln1g = (const float*)d_in[14]; const float* ln1b = (const float*)d_in[15];
    const float* ln2g = (const float*)d_in[16]; const float* ln2b = (const float*)d_in[17];
    const float* W1 = (const float*)d_in[18]; const float* b1 = (const float*)d_in[19];
    const float* W2 = (const float*)d_in[20]; const float* b2 = (const float*)d_in[21];
    float* out = (float*)d_out;

    // workspace layout (float offsets), ~155 MB total
    float* ws = (float*)d_ws;
    float* xln    = ws;                    // 1M floats
    float* wt     = ws + 1048576;          // 6.29M: WqT/WkT/WvT; later WoT/W1T/W2T
    float* WqT    = wt;
    float* WkT    = wt + 2097152;
    float* WvT    = wt + 4194304;
    float* WoT    = wt;                    // overlay after attention (2M)
    float* W1T    = wt + 2097152;          // 1M
    float* W2T    = wt + 3145728;          // 1M
    float* dbuf   = ws + 7340032;          // 1M
    float* Qh     = ws + 8388608;          // 1M
    float* Kh     = ws + 9437184;          // 1M
    float* VTh    = ws + 10485760;         // 1M
    float* S      = ws + 11534336;         // 4M (ffmid overlay after attention)
    float* ffmid  = S;
    float* mh     = ws + 15728640;         // 8M  [N][H*D]
    float* x1     = ws + 24117248;         // 1M
    float* h2     = ws + 25165824;         // 1M
    float* pvpart = ws + 26214400;         // 4M  (split-K partials, reused 3x)
    unsigned short* cb16 = (unsigned short*)(ws + 30408704); // 8M floats = 4 bf16 planes
    (void)in_sizes; (void)n_in; (void)out_size; (void)ws_size;

    const float scale = 0.04419417382415922f; // 1/sqrt(512)

    // 1) LN1 ; 2) edge dot table [E][P][H] ; 3) transpose Wq/Wk/Wv
    ln_kernel<<<N_NODES, 256, 0, stream>>>(x, ln1g, ln1b, xln);
    edge_d_kernel<<<NEDGE / 256, 256, 0, stream>>>(edge_attr, edge_vec, dbuf);
    k_transpose_qkv<<<dim3(16, 16, 24), 256, 0, stream>>>(Wq, Wk, Wv, WqT, WkT, WvT);

    // 4) per-head attention
    for (int h = 0; h < HEADS; h++) {
        if ((h & 3) == 0)    // refresh 4 bf16 bias planes per head group
            k_spatial_bias<<<(int)(NN / 256), 256, 0, stream>>>(
                b, path_idx, path_len, dbuf, cb16, h >> 2);

        k_qkvproj<<<dim3(N_NODES / BM, DIM / BN, 3), 512, 0, stream>>>(
            xln, WqT, WkT, WvT, bq, bk, bv, Qh, Kh, VTh, h);

        // S = scale*(Q K^T) + (b + c_h)   (bf16 bias plane folded in epilogue)
        k_mgemm<<<dim3(N_NODES / BM, N_NODES / BN), 512, 0, stream>>>(
            Qh, DIM, Kh, DIM, S, N_NODES, DIM, scale, nullptr, 0,
            nullptr, cb16 + (size_t)(h & 3) * NN, N_NODES, 0);
        k_softmax<<<N_NODES, 256, 0, stream>>>(S);

        // O_h = S @ V via split-K4, reduce into concatenated mh
        k_splitk<<<dim3(N_NODES / BM, DIM / BN, 4), 512, 0, stream>>>(
            S, N_NODES, VTh, N_NODES, pvpart, 512, 512);
        k_reduce4<<<(int)((size_t)N_NODES * DIM / 4 / 256), 256, 0, stream>>>(
            pvpart, mh + (size_t)h * DIM, HEADS * DIM, nullptr, nullptr, 0);
    }

    // 5) transpose Wo/W1/W2 (overlays WqT region — safe after attention)
    k_transpose<<<dim3(16, 128), 256, 0, stream>>>(Wo, WoT, HEADS * DIM, DIM);
    k_transpose<<<dim3(64, 16),  256, 0, stream>>>(W1, W1T, DIM, FFDIM);
    k_transpose<<<dim3(16, 64),  256, 0, stream>>>(W2, W2T, FFDIM, DIM);

    // 6) x1 = mh @ Wo + bo + x   (split-K4 over K=4096)
    k_splitk<<<dim3(N_NODES / BM, DIM / BN, 4), 512, 0, stream>>>(
        mh, HEADS * DIM, WoT, HEADS * DIM, pvpart, 1024, 1024);
    k_reduce4<<<(int)((size_t)N_NODES * DIM / 4 / 256), 256, 0, stream>>>(
        pvpart, x1, DIM, bo, x, DIM);

    // 7) LN2
    ln_kernel<<<N_NODES, 256, 0, stream>>>(x1, ln2g, ln2b, h2);

    // 8) ffmid = gelu(h2 @ W1 + b1)   (full grid 16x16)
    k_mgemm<<<dim3(N_NODES / BM, FFDIM / BN), 512, 0, stream>>>(
        h2, DIM, W1T, DIM, ffmid, FFDIM, DIM, 1.0f, b1, 1, nullptr, nullptr, 0, 1);

    // 9) out = ffmid @ W2 + b2 + x1   (split-K4 over K=2048)
    k_splitk<<<dim3(N_NODES / BM, DIM / BN, 4), 512, 0, stream>>>(
        ffmid, FFDIM, W2T, FFDIM, pvpart, 512, 512);
    k_reduce4<<<(int)((size_t)N_NODES * DIM / 4 / 256), 256, 0, stream>>>(
        pvpart, out, DIM, b2, x1, DIM);
}

// Round 7
// 984.625 us; speedup vs baseline: 3.3728x; 1.1099x over previous
//
#include <hip/hip_runtime.h>
#include <hip/hip_fp16.h>
#include <math.h>

#define N_NODES 2048
#define DIM     512
#define HEADS   8
#define FFDIM   2048
#define EDIM    64
#define PMAX    4
#define NEDGE   32768
#define NN      ((size_t)N_NODES * N_NODES)

// MFMA GEMM tile: 128x128, 8 waves (512 threads) as 2x4, wave tile 64x32.
#define BM 128
#define BN 128
#define BK 32
#define BKP (BK + 8)   // 80B row stride: frag b128 reads land 2-way (free, m136)

typedef __attribute__((ext_vector_type(8))) short bf16x8;
typedef __attribute__((ext_vector_type(8))) unsigned short u16x8;
typedef __attribute__((ext_vector_type(4))) float f32x4;

__device__ __forceinline__ unsigned short f2bf_rne(float f) {
    unsigned int u = __float_as_uint(f);
    u += 0x7FFFu + ((u >> 16) & 1u);
    return (unsigned short)(u >> 16);
}

// ---------------------------------------------------------------------------
// LayerNorm: one block (256 threads) per row of 512 floats.
// ---------------------------------------------------------------------------
__global__ __launch_bounds__(256)
void ln_kernel(const float* __restrict__ x, const float* __restrict__ g,
               const float* __restrict__ beta, float* __restrict__ out) {
    const int row = blockIdx.x;
    const int t = threadIdx.x;
    const float* xr = x + (size_t)row * DIM;
    const float v0 = xr[t];
    const float v1 = xr[t + 256];
    __shared__ float red[4];
    const int lane = t & 63, wid = t >> 6;

    float s = v0 + v1;
    #pragma unroll
    for (int o = 32; o > 0; o >>= 1) s += __shfl_xor(s, o);
    if (lane == 0) red[wid] = s;
    __syncthreads();
    const float mu = (red[0] + red[1] + red[2] + red[3]) * (1.0f / DIM);
    __syncthreads();

    const float d0 = v0 - mu, d1 = v1 - mu;
    float vs = d0 * d0 + d1 * d1;
    #pragma unroll
    for (int o = 32; o > 0; o >>= 1) vs += __shfl_xor(vs, o);
    if (lane == 0) red[wid] = vs;
    __syncthreads();
    const float var = (red[0] + red[1] + red[2] + red[3]) * (1.0f / DIM);
    const float inv = 1.0f / sqrtf(var + 1e-5f);

    out[(size_t)row * DIM + t]       = d0 * inv * g[t] + beta[t];
    out[(size_t)row * DIM + t + 256] = d1 * inv * g[t + 256] + beta[t + 256];
}

// ---------------------------------------------------------------------------
// d2[e][p][h] = sum_f edge_attr[e][f] * edge_vec[h][p][f]   (layout [E][P][H])
// ---------------------------------------------------------------------------
__global__ __launch_bounds__(256)
void edge_d_kernel(const float* __restrict__ edge_attr,
                   const float* __restrict__ edge_vec,
                   float* __restrict__ dout) {
    __shared__ float ev[HEADS * PMAX * EDIM]; // 2048 floats
    const int t = threadIdx.x;
    for (int i = t; i < HEADS * PMAX * EDIM; i += 256) ev[i] = edge_vec[i];
    __syncthreads();

    const int e = blockIdx.x * 256 + t;
    float acc[32];
    #pragma unroll
    for (int i = 0; i < 32; i++) acc[i] = 0.0f;

    const float4* ea = (const float4*)(edge_attr + (size_t)e * EDIM);
    #pragma unroll
    for (int f4 = 0; f4 < EDIM / 4; f4++) {
        const float4 a = ea[f4];
        #pragma unroll
        for (int hp = 0; hp < 32; hp++) {   // hp = h*4+p
            const float4 v = ((const float4*)(ev + hp * EDIM))[f4];
            acc[hp] += a.x * v.x + a.y * v.y + a.z * v.z + a.w * v.w;
        }
    }
    float* o = dout + (size_t)e * 32;
    #pragma unroll
    for (int hp = 0; hp < 32; hp++)
        o[(hp & 3) * 8 + (hp >> 2)] = acc[hp];   // [p][h]
}

// ---------------------------------------------------------------------------
// Fused spatial-bias: ONE pass over path data writes all 8 fp16 planes.
// cb[h][i][j] = fp16( b[i][j] + (len>0 ? sum_p d2[e_p][p][h]/len : 0) )
// ---------------------------------------------------------------------------
__global__ __launch_bounds__(256)
void k_spatial_bias8(const float* __restrict__ b,
                     const int* __restrict__ path_idx,
                     const int* __restrict__ path_len,
                     const float* __restrict__ d2,
                     __half* __restrict__ cb) {
    const size_t idx = (size_t)blockIdx.x * 256 + threadIdx.x;   // flat over N*N
    const int len = path_len[idx];
    const float bb = b[idx];
    float c[8];
    #pragma unroll
    for (int h = 0; h < 8; h++) c[h] = 0.0f;
    if (len > 0) {
        const int4 pi = ((const int4*)path_idx)[idx];
        const int e[4] = {pi.x, pi.y, pi.z, pi.w};
        #pragma unroll
        for (int p = 0; p < 4; p++) {
            if (p < len) {
                const float4 v0 = *(const float4*)(d2 + (size_t)e[p] * 32 + p * 8);
                const float4 v1 = *(const float4*)(d2 + (size_t)e[p] * 32 + p * 8 + 4);
                c[0] += v0.x; c[1] += v0.y; c[2] += v0.z; c[3] += v0.w;
                c[4] += v1.x; c[5] += v1.y; c[6] += v1.z; c[7] += v1.w;
            }
        }
        const float inv = 1.0f / (float)len;
        #pragma unroll
        for (int h = 0; h < 8; h++) c[h] *= inv;
    }
    #pragma unroll
    for (int h = 0; h < 8; h++)
        cb[(size_t)h * NN + idx] = __float2half(bb + c[h]);
}

// Fallback: 4-head group version (fits smaller workspace).
__global__ __launch_bounds__(256)
void k_spatial_bias4(const float* __restrict__ b,
                     const int* __restrict__ path_idx,
                     const int* __restrict__ path_len,
                     const float* __restrict__ d2,
                     __half* __restrict__ cb, int hg) {
    const size_t idx = (size_t)blockIdx.x * 256 + threadIdx.x;
    const int len = path_len[idx];
    const float bb = b[idx];
    float c0 = 0.f, c1 = 0.f, c2 = 0.f, c3 = 0.f;
    if (len > 0) {
        const int4 pi = ((const int4*)path_idx)[idx];
        const int e[4] = {pi.x, pi.y, pi.z, pi.w};
        #pragma unroll
        for (int p = 0; p < 4; p++) {
            if (p < len) {
                const float4 v = *(const float4*)(d2 + (size_t)e[p] * 32 + p * 8 + hg * 4);
                c0 += v.x; c1 += v.y; c2 += v.z; c3 += v.w;
            }
        }
        const float inv = 1.0f / (float)len;
        c0 *= inv; c1 *= inv; c2 *= inv; c3 *= inv;
    }
    cb[0 * NN + idx] = __float2half(bb + c0);
    cb[1 * NN + idx] = __float2half(bb + c1);
    cb[2 * NN + idx] = __float2half(bb + c2);
    cb[3 * NN + idx] = __float2half(bb + c3);
}

// ---------------------------------------------------------------------------
// fp32 -> bf16 splits. Trunc-based hi/lo (3-pass) and RNE (1-pass).
// ---------------------------------------------------------------------------
__device__ __forceinline__ void cvt8(float4 a, float4 b, u16x8* hi, u16x8* lo) {
    float v[8] = {a.x, a.y, a.z, a.w, b.x, b.y, b.z, b.w};
    u16x8 h, l;
    #pragma unroll
    for (int i = 0; i < 8; i++) {
        const unsigned int u = __float_as_uint(v[i]);
        h[i] = (unsigned short)(u >> 16);
        const float r = v[i] - __uint_as_float(u & 0xFFFF0000u);
        l[i] = (unsigned short)(__float_as_uint(r) >> 16);
    }
    *hi = h; *lo = l;
}

__device__ __forceinline__ u16x8 cvt8_rne(float4 a, float4 b) {
    float v[8] = {a.x, a.y, a.z, a.w, b.x, b.y, b.z, b.w};
    u16x8 h;
    #pragma unroll
    for (int i = 0; i < 8; i++) h[i] = f2bf_rne(v[i]);
    return h;
}

// ---------------------------------------------------------------------------
// MFMA GEMM (NT): C = alpha*(A[M][K] B[N][K]^T) [+bias][+res]
// PASSES=3: split hi/lo bf16, 3 MFMA passes (~fp32). PASSES=1: RNE bf16.
// 128x128 tile, 512 threads = 8 waves (2x4), wave tile 64x32 = 4x2 frags.
// biasMode: 0 none, 1 bias[col], 2 bias[row]. resF fp32 / resH fp16 residual.
// ---------------------------------------------------------------------------
template<int PASSES>
__device__ __forceinline__
void mgemm_body(int rowBase, int colBase,
                const float* __restrict__ A, int lda,
                const float* __restrict__ B, int ldb,
                float* __restrict__ C, int ldc, int K, float alpha,
                const float* __restrict__ bias, int biasMode,
                const float* __restrict__ resF,
                const __half* __restrict__ resH, int ldr, int gelu_flag) {
    __shared__ __attribute__((aligned(16))) unsigned short As_h[BM * BKP];
    __shared__ __attribute__((aligned(16))) unsigned short Bs_h[BN * BKP];
    __shared__ __attribute__((aligned(16))) unsigned short As_l[PASSES == 3 ? BM * BKP : 8];
    __shared__ __attribute__((aligned(16))) unsigned short Bs_l[PASSES == 3 ? BN * BKP : 8];

    const int t = threadIdx.x;        // 0..511
    const int l = t & 63;
    const int wave = t >> 6;          // 0..7
    const int wr = wave >> 2;         // 0..1 (row half)
    const int wc = wave & 3;          // 0..3 (col quarter)

    // staging: thread t loads 8 consecutive floats of row sRow (A and B tiles)
    const int sRow = t >> 2, sCol = (t & 3) * 8;
    const float* Ag = A + (size_t)(rowBase + sRow) * lda + sCol;
    const float* Bg = B + (size_t)(colBase + sRow) * ldb + sCol;

    f32x4 acc[4][2] = {};

    float4 pa0 = *(const float4*)(Ag);
    float4 pa1 = *(const float4*)(Ag + 4);
    float4 pb0 = *(const float4*)(Bg);
    float4 pb1 = *(const float4*)(Bg + 4);

    const int fr = l & 15;          // frag row within 16
    const int kg = (l >> 4) * 8;    // k-group start (elements)

    for (int k0 = 0; k0 < K; k0 += BK) {
        if (PASSES == 3) {
            u16x8 ah, al, bh, bl;
            cvt8(pa0, pa1, &ah, &al);
            cvt8(pb0, pb1, &bh, &bl);
            __syncthreads();
            *(u16x8*)&As_h[sRow * BKP + sCol] = ah;
            *(u16x8*)&As_l[sRow * BKP + sCol] = al;
            *(u16x8*)&Bs_h[sRow * BKP + sCol] = bh;
            *(u16x8*)&Bs_l[sRow * BKP + sCol] = bl;
        } else {
            const u16x8 ah = cvt8_rne(pa0, pa1);
            const u16x8 bh = cvt8_rne(pb0, pb1);
            __syncthreads();
            *(u16x8*)&As_h[sRow * BKP + sCol] = ah;
            *(u16x8*)&Bs_h[sRow * BKP + sCol] = bh;
        }
        __syncthreads();
        if (k0 + BK < K) {                     // prefetch next tiles
            pa0 = *(const float4*)(Ag + k0 + BK);
            pa1 = *(const float4*)(Ag + k0 + BK + 4);
            pb0 = *(const float4*)(Bg + k0 + BK);
            pb1 = *(const float4*)(Bg + k0 + BK + 4);
        }
        bf16x8 a_h[4], b_h[2];
        #pragma unroll
        for (int fm = 0; fm < 4; fm++)
            a_h[fm] = *(const bf16x8*)&As_h[(wr * 64 + fm * 16 + fr) * BKP + kg];
        #pragma unroll
        for (int fn = 0; fn < 2; fn++)
            b_h[fn] = *(const bf16x8*)&Bs_h[(wc * 32 + fn * 16 + fr) * BKP + kg];

        if (PASSES == 3) {
            bf16x8 a_l[4], b_l[2];
            #pragma unroll
            for (int fm = 0; fm < 4; fm++)
                a_l[fm] = *(const bf16x8*)&As_l[(wr * 64 + fm * 16 + fr) * BKP + kg];
            #pragma unroll
            for (int fn = 0; fn < 2; fn++)
                b_l[fn] = *(const bf16x8*)&Bs_l[(wc * 32 + fn * 16 + fr) * BKP + kg];
            #pragma unroll
            for (int fm = 0; fm < 4; fm++)
                #pragma unroll
                for (int fn = 0; fn < 2; fn++) {
                    acc[fm][fn] = __builtin_amdgcn_mfma_f32_16x16x32_bf16(a_h[fm], b_h[fn], acc[fm][fn], 0, 0, 0);
                    acc[fm][fn] = __builtin_amdgcn_mfma_f32_16x16x32_bf16(a_h[fm], b_l[fn], acc[fm][fn], 0, 0, 0);
                    acc[fm][fn] = __builtin_amdgcn_mfma_f32_16x16x32_bf16(a_l[fm], b_h[fn], acc[fm][fn], 0, 0, 0);
                }
        } else {
            #pragma unroll
            for (int fm = 0; fm < 4; fm++)
                #pragma unroll
                for (int fn = 0; fn < 2; fn++)
                    acc[fm][fn] = __builtin_amdgcn_mfma_f32_16x16x32_bf16(a_h[fm], b_h[fn], acc[fm][fn], 0, 0, 0);
        }
    }

    // epilogue: C/D layout col=lane&15, row=(lane>>4)*4+reg  [m89-verified]
    #pragma unroll
    for (int fm = 0; fm < 4; fm++) {
        const int r0 = rowBase + wr * 64 + fm * 16 + (l >> 4) * 4;
        #pragma unroll
        for (int fn = 0; fn < 2; fn++) {
            const int c0 = colBase + wc * 32 + fn * 16 + (l & 15);
            #pragma unroll
            for (int r = 0; r < 4; r++) {
                float v = acc[fm][fn][r] * alpha;
                const int rr = r0 + r;
                if (biasMode == 1) v += bias[c0];
                else if (biasMode == 2) v += bias[rr];
                if (gelu_flag) v = 0.5f * v * (1.0f + erff(v * 0.70710678118654752f));
                if (resF) v += resF[(size_t)rr * ldr + c0];
                if (resH) v += __half2float(resH[(size_t)rr * ldr + c0]);
                C[(size_t)rr * ldc + c0] = v;
            }
        }
    }
}

__global__ __launch_bounds__(512, 2)
void k_mgemm3(const float* __restrict__ A, int lda, const float* __restrict__ B, int ldb,
              float* __restrict__ C, int ldc, int K, float alpha,
              const float* __restrict__ bias, int biasMode,
              const float* __restrict__ resF, int ldr, int gelu_flag) {
    mgemm_body<3>(blockIdx.x * BM, blockIdx.y * BN,
                  A, lda, B, ldb, C, ldc, K, alpha, bias, biasMode, resF, nullptr, ldr, gelu_flag);
}

// QK^T single-pass bf16 with fp16 bias-plane residual, alpha = 1/sqrt(D).
__global__ __launch_bounds__(512, 2)
void k_qkt(const float* __restrict__ Q, const float* __restrict__ K,
           float* __restrict__ S, float alpha, const __half* __restrict__ cb) {
    mgemm_body<1>(blockIdx.x * BM, blockIdx.y * BN,
                  Q, DIM, K, DIM, S, N_NODES, DIM, alpha,
                  nullptr, 0, nullptr, cb, N_NODES, 0);
}

// Q, K and V^T projections for head h in one launch (single-pass bf16): grid (16, 4, 3).
__global__ __launch_bounds__(512, 2)
void k_qkvproj(const float* __restrict__ xln,
               const float* __restrict__ WqT, const float* __restrict__ WkT,
               const float* __restrict__ WvT,
               const float* __restrict__ bq, const float* __restrict__ bk,
               const float* __restrict__ bv,
               float* __restrict__ Qh, float* __restrict__ Kh,
               float* __restrict__ VTh, int h) {
    const int z = blockIdx.z;
    if (z == 0)
        mgemm_body<1>(blockIdx.x * BM, blockIdx.y * BN,
                      xln, DIM, WqT + (size_t)h * DIM * DIM, DIM, Qh, DIM, DIM, 1.0f,
                      bq + h * DIM, 1, nullptr, nullptr, 0, 0);
    else if (z == 1)
        mgemm_body<1>(blockIdx.x * BM, blockIdx.y * BN,
                      xln, DIM, WkT + (size_t)h * DIM * DIM, DIM, Kh, DIM, DIM, 1.0f,
                      bk + h * DIM, 1, nullptr, nullptr, 0, 0);
    else
        mgemm_body<1>(blockIdx.y * BM, blockIdx.x * BN,   // M=512 side from y
                      WvT + (size_t)h * DIM * DIM, DIM, xln, DIM, VTh, N_NODES, DIM, 1.0f,
                      bv + h * DIM, 2, nullptr, nullptr, 0, 0);
}

// Split-K=4 GEMM into partial planes: grid (16, 4, 4). Template on passes.
__global__ __launch_bounds__(512, 2)
void k_splitk1(const float* __restrict__ A, int lda, const float* __restrict__ B, int ldb,
               float* __restrict__ part, int Kslice, int Koff) {
    const int z = blockIdx.z;
    mgemm_body<1>(blockIdx.x * BM, blockIdx.y * BN,
                  A + (size_t)z * Koff, lda, B + (size_t)z * Koff, ldb,
                  part + (size_t)z * N_NODES * DIM, DIM, Kslice, 1.0f,
                  nullptr, 0, nullptr, nullptr, 0, 0);
}

__global__ __launch_bounds__(512, 2)
void k_splitk3(const float* __restrict__ A, int lda, const float* __restrict__ B, int ldb,
               float* __restrict__ part, int Kslice, int Koff) {
    const int z = blockIdx.z;
    mgemm_body<3>(blockIdx.x * BM, blockIdx.y * BN,
                  A + (size_t)z * Koff, lda, B + (size_t)z * Koff, ldb,
                  part + (size_t)z * N_NODES * DIM, DIM, Kslice, 1.0f,
                  nullptr, 0, nullptr, nullptr, 0, 0);
}

// Sum 4 partials + optional bias[col] + optional fp32 residual -> dst (ld dstLd).
__global__ __launch_bounds__(256)
void k_reduce4(const float* __restrict__ part, float* __restrict__ dst, int dstLd,
               const float* __restrict__ bias, const float* __restrict__ res, int resLd) {
    const size_t q = (size_t)blockIdx.x * 256 + threadIdx.x;   // float4 index
    const size_t CH = (size_t)N_NODES * DIM / 4;
    const float4 a0 = ((const float4*)part)[q];
    const float4 a1 = ((const float4*)part)[q + CH];
    const float4 a2 = ((const float4*)part)[q + 2 * CH];
    const float4 a3 = ((const float4*)part)[q + 3 * CH];
    float4 s;
    s.x = a0.x + a1.x + a2.x + a3.x;
    s.y = a0.y + a1.y + a2.y + a3.y;
    s.z = a0.z + a1.z + a2.z + a3.z;
    s.w = a0.w + a1.w + a2.w + a3.w;
    const size_t el = q * 4;
    const size_t r = el >> 9, c = el & 511;                    // [2048][512]
    if (bias) { s.x += bias[c]; s.y += bias[c + 1]; s.z += bias[c + 2]; s.w += bias[c + 3]; }
    if (res) {
        const float4 rv = *(const float4*)&res[r * resLd + c];
        s.x += rv.x; s.y += rv.y; s.z += rv.z; s.w += rv.w;
    }
    *(float4*)&dst[r * (size_t)dstLd + c] = s;
}

// ---------------------------------------------------------------------------
// 32x32 tiled fp32 transpose: dst[C][R] = src[R][C]^T
// ---------------------------------------------------------------------------
__device__ __forceinline__
void transpose_body(const float* __restrict__ src, float* __restrict__ dst, int R, int C) {
    __shared__ float tile[32][33];
    const int t = threadIdx.x;
    const int tx = t & 31, ty = t >> 5;
    const int x0 = blockIdx.x * 32, y0 = blockIdx.y * 32;
    #pragma unroll
    for (int i = 0; i < 4; i++)
        tile[ty + 8 * i][tx] = src[(size_t)(y0 + ty + 8 * i) * C + x0 + tx];
    __syncthreads();
    #pragma unroll
    for (int i = 0; i < 4; i++)
        dst[(size_t)(x0 + ty + 8 * i) * R + y0 + tx] = tile[tx][ty + 8 * i];
}

__global__ __launch_bounds__(256)
void k_transpose(const float* __restrict__ src, float* __restrict__ dst, int R, int C) {
    transpose_body(src, dst, R, C);
}

__global__ __launch_bounds__(256)
void k_transpose_qkv(const float* __restrict__ Wq, const float* __restrict__ Wk,
                     const float* __restrict__ Wv,
                     float* __restrict__ WqT, float* __restrict__ WkT,
                     float* __restrict__ WvT) {
    const int z = blockIdx.z;
    const int w = z >> 3, h = z & 7;
    const float* src = (w == 0 ? Wq : w == 1 ? Wk : Wv) + (size_t)h * DIM * DIM;
    float* dst       = (w == 0 ? WqT : w == 1 ? WkT : WvT) + (size_t)h * DIM * DIM;
    transpose_body(src, dst, DIM, DIM);
}

// ---------------------------------------------------------------------------
// Plain in-place row softmax (bias folded in by the QK^T epilogue).
// ---------------------------------------------------------------------------
__global__ __launch_bounds__(256)
void k_softmax(float* __restrict__ S) {
    const int i = blockIdx.x;
    const int t = threadIdx.x;
    const int lane = t & 63, wid = t >> 6;
    __shared__ float red[4];

    float v[8];
    float m = -1e30f;
    #pragma unroll
    for (int k = 0; k < 8; k++) {
        v[k] = S[(size_t)i * N_NODES + t + k * 256];
        m = fmaxf(m, v[k]);
    }
    #pragma unroll
    for (int o = 32; o > 0; o >>= 1) m = fmaxf(m, __shfl_xor(m, o));
    if (lane == 0) red[wid] = m;
    __syncthreads();
    m = fmaxf(fmaxf(red[0], red[1]), fmaxf(red[2], red[3]));
    __syncthreads();

    float s = 0.0f;
    #pragma unroll
    for (int k = 0; k < 8; k++) { v[k] = expf(v[k] - m); s += v[k]; }
    #pragma unroll
    for (int o = 32; o > 0; o >>= 1) s += __shfl_xor(s, o);
    if (lane == 0) red[wid] = s;
    __syncthreads();
    s = red[0] + red[1] + red[2] + red[3];
    const float inv = 1.0f / s;
    #pragma unroll
    for (int k = 0; k < 8; k++)
        S[(size_t)i * N_NODES + t + k * 256] = v[k] * inv;
}

// ---------------------------------------------------------------------------
extern "C" void kernel_launch(void* const* d_in, const int* in_sizes, int n_in,
                              void* d_out, int out_size, void* d_ws, size_t ws_size,
                              hipStream_t stream) {
    const float* x         = (const float*)d_in[0];
    const float* edge_attr = (const float*)d_in[1];
    const float* b         = (const float*)d_in[2];
    const int*   path_idx  = (const int*)d_in[3];
    const int*   path_len  = (const int*)d_in[4];
    const float* Wq = (const float*)d_in[5];  const float* bq = (const float*)d_in[6];
    const float* Wk = (const float*)d_in[7];  const float* bk = (const float*)d_in[8];
    const float* Wv = (const float*)d_in[9];  const float* bv = (const float*)d_in[10];
    const float* edge_vec = (const float*)d_in[11];
    const float* Wo = (const float*)d_in[12]; const float* bo = (const float*)d_in[13];
    const float* ln1g = (const float*)d_in[14]; const float* ln1b = (const float*)d_in[15];
    const float* ln2g = (const float*)d_in[16]; const float* ln2b = (const float*)d_in[17];
    const float* W1 = (const float*)d_in[18]; const float* b1 = (const float*)d_in[19];
    const float* W2 = (const float*)d_in[20]; const float* b2 = (const float*)d_in[21];
    float* out = (float*)d_out;

    // workspace layout (float offsets)
    float* ws = (float*)d_ws;
    float* xln    = ws;                    // 1M floats
    float* wt     = ws + 1048576;          // 6.29M: WqT/WkT/WvT; later WoT/W1T/W2T
    float* WqT    = wt;
    float* WkT    = wt + 2097152;
    float* WvT    = wt + 4194304;
    float* WoT    = wt;                    // overlay after attention (2M)
    float* W1T    = wt + 2097152;          // 1M
    float* W2T    = wt + 3145728;          // 1M
    float* Qh     = ws + 7340032;          // 1M
    float* Kh     = ws + 8388608;          // 1M
    float* VTh    = ws + 9437184;          // 1M
    float* S      = ws + 10485760;         // 4M
    float* mh     = ws + 14680064;         // 8M  [N][H*D]
    float* pvpart = ws + 23068672;         // 4M  (split-K partials, reused 3x)
    float* dbuf   = pvpart;                // 1M  (dead before first split-K)
    __half* cb    = (__half*)(ws + 27262976); // fp16 planes: 8 (big) or 4 (small)
    // post-attention overlays (regions dead by then)
    float* x1     = S;                     // 1M
    float* h2     = S + 1048576;           // 1M
    float* ffmid  = mh;                    // 4M
    // big path: 8 fp16 planes end at float-offset 27262976+16777216 = 44040192
    const int big = (ws_size >= (size_t)44040192 * 4);
    (void)in_sizes; (void)n_in; (void)out_size;

    const float scale = 0.04419417382415922f; // 1/sqrt(512)

    // 1) LN1 ; 2) edge dot table [E][P][H] ; 3) transpose Wq/Wk/Wv
    ln_kernel<<<N_NODES, 256, 0, stream>>>(x, ln1g, ln1b, xln);
    edge_d_kernel<<<NEDGE / 256, 256, 0, stream>>>(edge_attr, edge_vec, dbuf);
    k_transpose_qkv<<<dim3(16, 16, 24), 256, 0, stream>>>(Wq, Wk, Wv, WqT, WkT, WvT);

    if (big)   // all 8 bias planes in ONE pass over path data
        k_spatial_bias8<<<(int)(NN / 256), 256, 0, stream>>>(b, path_idx, path_len, dbuf, cb);

    // 4) per-head attention
    for (int h = 0; h < HEADS; h++) {
        if (!big && (h & 3) == 0)
            k_spatial_bias4<<<(int)(NN / 256), 256, 0, stream>>>(
                b, path_idx, path_len, dbuf, cb, h >> 2);
        const __half* cbplane = cb + (size_t)(big ? h : (h & 3)) * NN;

        k_qkvproj<<<dim3(N_NODES / BM, DIM / BN, 3), 512, 0, stream>>>(
            xln, WqT, WkT, WvT, bq, bk, bv, Qh, Kh, VTh, h);

        // S = scale*(Q K^T) + (b + c_h)
        k_qkt<<<dim3(N_NODES / BM, N_NODES / BN), 512, 0, stream>>>(Qh, Kh, S, scale, cbplane);
        k_softmax<<<N_NODES, 256, 0, stream>>>(S);

        // O_h = S @ V via split-K4 (single-pass bf16), reduce into concatenated mh
        k_splitk1<<<dim3(N_NODES / BM, DIM / BN, 4), 512, 0, stream>>>(
            S, N_NODES, VTh, N_NODES, pvpart, 512, 512);
        k_reduce4<<<(int)((size_t)N_NODES * DIM / 4 / 256), 256, 0, stream>>>(
            pvpart, mh + (size_t)h * DIM, HEADS * DIM, nullptr, nullptr, 0);
    }

    // 5) transpose Wo/W1/W2 (overlays WqT region — safe after attention)
    k_transpose<<<dim3(16, 128), 256, 0, stream>>>(Wo, WoT, HEADS * DIM, DIM);
    k_transpose<<<dim3(64, 16),  256, 0, stream>>>(W1, W1T, DIM, FFDIM);
    k_transpose<<<dim3(16, 64),  256, 0, stream>>>(W2, W2T, FFDIM, DIM);

    // 6) x1 = mh @ Wo + bo + x   (split-K4 over K=4096, 3-pass)
    k_splitk3<<<dim3(N_NODES / BM, DIM / BN, 4), 512, 0, stream>>>(
        mh, HEADS * DIM, WoT, HEADS * DIM, pvpart, 1024, 1024);
    k_reduce4<<<(int)((size_t)N_NODES * DIM / 4 / 256), 256, 0, stream>>>(
        pvpart, x1, DIM, bo, x, DIM);

    // 7) LN2
    ln_kernel<<<N_NODES, 256, 0, stream>>>(x1, ln2g, ln2b, h2);

    // 8) ffmid = gelu(h2 @ W1 + b1)   (3-pass, full grid 16x16; mh dead -> ffmid)
    k_mgemm3<<<dim3(N_NODES / BM, FFDIM / BN), 512, 0, stream>>>(
        h2, DIM, W1T, DIM, ffmid, FFDIM, DIM, 1.0f, b1, 1, nullptr, 0, 1);

    // 9) out = ffmid @ W2 + b2 + x1   (split-K4 over K=2048, 3-pass)
    k_splitk3<<<dim3(N_NODES / BM, DIM / BN, 4), 512, 0, stream>>>(
        ffmid, FFDIM, W2T, FFDIM, pvpart, 512, 512);
    k_reduce4<<<(int)((size_t)N_NODES * DIM / 4 / 256), 256, 0, stream>>>(
        pvpart, out, DIM, b2, x1, DIM);
}

// Round 8
// 741.228 us; speedup vs baseline: 4.4803x; 1.3284x over previous
//
#include <hip/hip_runtime.h>
#include <math.h>

#define N_NODES 2048
#define DIM     512
#define HEADS   8
#define FFDIM   2048
#define EDIM    64
#define PMAX    4
#define NEDGE   32768
#define NN      ((size_t)N_NODES * N_NODES)

// fp16 MFMA GEMM tile: 128x128, 8 waves (512 thr) as 2x4, wave tile 64x32.
#define BM 128
#define BN 128
#define BK 64
#define BKP (BK + 8)   // 144B row stride: b128 accesses land 2-way (free, m136)

typedef _Float16 half_t;
typedef __attribute__((ext_vector_type(8))) _Float16 f16x8;
typedef __attribute__((ext_vector_type(4))) _Float16 f16x4;
typedef __attribute__((ext_vector_type(8))) unsigned short u16x8;
typedef __attribute__((ext_vector_type(4))) float f32x4;

// ---------------------------------------------------------------------------
// LayerNorm: one block per row of 512 floats; fp16 output.
// ---------------------------------------------------------------------------
__global__ __launch_bounds__(256)
void ln_kernel(const float* __restrict__ x, const float* __restrict__ g,
               const float* __restrict__ beta, half_t* __restrict__ out) {
    const int row = blockIdx.x;
    const int t = threadIdx.x;
    const float* xr = x + (size_t)row * DIM;
    const float v0 = xr[t];
    const float v1 = xr[t + 256];
    __shared__ float red[4];
    const int lane = t & 63, wid = t >> 6;

    float s = v0 + v1;
    #pragma unroll
    for (int o = 32; o > 0; o >>= 1) s += __shfl_xor(s, o);
    if (lane == 0) red[wid] = s;
    __syncthreads();
    const float mu = (red[0] + red[1] + red[2] + red[3]) * (1.0f / DIM);
    __syncthreads();

    const float d0 = v0 - mu, d1 = v1 - mu;
    float vs = d0 * d0 + d1 * d1;
    #pragma unroll
    for (int o = 32; o > 0; o >>= 1) vs += __shfl_xor(vs, o);
    if (lane == 0) red[wid] = vs;
    __syncthreads();
    const float var = (red[0] + red[1] + red[2] + red[3]) * (1.0f / DIM);
    const float inv = 1.0f / sqrtf(var + 1e-5f);

    out[(size_t)row * DIM + t]       = (half_t)(d0 * inv * g[t] + beta[t]);
    out[(size_t)row * DIM + t + 256] = (half_t)(d1 * inv * g[t + 256] + beta[t + 256]);
}

// ---------------------------------------------------------------------------
// d2[e][p][h] fp16 = sum_f edge_attr[e][f] * edge_vec[h][p][f]  (layout [E][P][H])
// 16B granule (e,p) covers all 8 heads -> single gather load downstream.
// ---------------------------------------------------------------------------
__global__ __launch_bounds__(256)
void edge_d_kernel(const float* __restrict__ edge_attr,
                   const float* __restrict__ edge_vec,
                   half_t* __restrict__ dout) {
    __shared__ float ev[HEADS * PMAX * EDIM]; // 2048 floats
    const int t = threadIdx.x;
    for (int i = t; i < HEADS * PMAX * EDIM; i += 256) ev[i] = edge_vec[i];
    __syncthreads();

    const int e = blockIdx.x * 256 + t;
    float acc[32];
    #pragma unroll
    for (int i = 0; i < 32; i++) acc[i] = 0.0f;

    const float4* ea = (const float4*)(edge_attr + (size_t)e * EDIM);
    #pragma unroll
    for (int f4 = 0; f4 < EDIM / 4; f4++) {
        const float4 a = ea[f4];
        #pragma unroll
        for (int hp = 0; hp < 32; hp++) {   // hp = h*4+p
            const float4 v = ((const float4*)(ev + hp * EDIM))[f4];
            acc[hp] += a.x * v.x + a.y * v.y + a.z * v.z + a.w * v.w;
        }
    }
    half_t* o = dout + (size_t)e * 32;
    #pragma unroll
    for (int hp = 0; hp < 32; hp++)
        o[(hp & 3) * 8 + (hp >> 2)] = (half_t)acc[hp];   // [p][h]
}

// ---------------------------------------------------------------------------
// Spatial-bias: one pass writes 8 fp16 planes. 2 positions per thread (ILP).
// cb[h][i] = fp16( b[i] + (len>0 ? sum_p d2[e_p][p][h]/len : 0) )
// ---------------------------------------------------------------------------
__device__ __forceinline__ void sbias_pos(const float* __restrict__ b,
                                          const int* __restrict__ path_idx,
                                          const int* __restrict__ path_len,
                                          const half_t* __restrict__ d2,
                                          half_t* __restrict__ cb, size_t idx) {
    const int len = path_len[idx];
    const float bb = b[idx];
    float c[8];
    #pragma unroll
    for (int h = 0; h < 8; h++) c[h] = 0.0f;
    if (len > 0) {
        const int4 pi = ((const int4*)path_idx)[idx];
        const int e[4] = {pi.x, pi.y, pi.z, pi.w};
        #pragma unroll
        for (int p = 0; p < 4; p++) {
            if (p < len) {
                const f16x8 v = *(const f16x8*)&d2[(size_t)e[p] * 32 + p * 8];
                #pragma unroll
                for (int h = 0; h < 8; h++) c[h] += (float)v[h];
            }
        }
        const float inv = 1.0f / (float)len;
        #pragma unroll
        for (int h = 0; h < 8; h++) c[h] *= inv;
    }
    #pragma unroll
    for (int h = 0; h < 8; h++)
        cb[(size_t)h * NN + idx] = (half_t)(bb + c[h]);
}

__global__ __launch_bounds__(256)
void k_spatial_bias8(const float* __restrict__ b,
                     const int* __restrict__ path_idx,
                     const int* __restrict__ path_len,
                     const half_t* __restrict__ d2,
                     half_t* __restrict__ cb) {
    const size_t i0 = (size_t)blockIdx.x * 256 + threadIdx.x;
    sbias_pos(b, path_idx, path_len, d2, cb, i0);
    sbias_pos(b, path_idx, path_len, d2, cb, i0 + NN / 2);
}

// Fallback (small ws): 4 planes for head group hg.
__global__ __launch_bounds__(256)
void k_spatial_bias4(const float* __restrict__ b,
                     const int* __restrict__ path_idx,
                     const int* __restrict__ path_len,
                     const half_t* __restrict__ d2,
                     half_t* __restrict__ cb, int hg) {
    const size_t idx = (size_t)blockIdx.x * 256 + threadIdx.x;
    const int len = path_len[idx];
    const float bb = b[idx];
    float c[4] = {0.f, 0.f, 0.f, 0.f};
    if (len > 0) {
        const int4 pi = ((const int4*)path_idx)[idx];
        const int e[4] = {pi.x, pi.y, pi.z, pi.w};
        #pragma unroll
        for (int p = 0; p < 4; p++) {
            if (p < len) {
                const f16x8 v = *(const f16x8*)&d2[(size_t)e[p] * 32 + p * 8];
                #pragma unroll
                for (int h = 0; h < 4; h++) c[h] += (float)v[hg * 4 + h];
            }
        }
        const float inv = 1.0f / (float)len;
        #pragma unroll
        for (int h = 0; h < 4; h++) c[h] *= inv;
    }
    #pragma unroll
    for (int h = 0; h < 4; h++)
        cb[(size_t)h * NN + idx] = (half_t)(bb + c[h]);
}

// ---------------------------------------------------------------------------
// fp16 MFMA GEMM (NT): C = alpha*(A[M][K] B[N][K]^T) [+bias][+resH][gelu]
// A,B fp16 in memory; staging is two 16B copies/thread/K-tile (no cvt).
// BK=64: inner loop does 2 k-chunks of 32 -> 16 MFMA/wave per barrier pair.
// biasMode: 0 none, 1 bias[col], 2 bias[row]. OUT16: fp16 C, else fp32.
// ---------------------------------------------------------------------------
template<int OUT16>
__device__ __forceinline__
void hgemm_body(int rowBase, int colBase,
                const half_t* __restrict__ A, int lda,
                const half_t* __restrict__ B, int ldb,
                void* __restrict__ Cout, int ldc, int K, float alpha,
                const float* __restrict__ bias, int biasMode,
                const half_t* __restrict__ resH, int ldr, int gelu_flag) {
    __shared__ __attribute__((aligned(16))) half_t As[BM * BKP];  // 18.4 KB
    __shared__ __attribute__((aligned(16))) half_t Bs[BN * BKP];

    const int t = threadIdx.x;        // 0..511
    const int l = t & 63;
    const int wave = t >> 6;
    const int wr = wave >> 2;         // 0..1 row half
    const int wc = wave & 3;          // 0..3 col quarter

    // staging: thread t covers 16 fp16 of row sRow (two u16x8 loads)
    const int sRow = t >> 2, sCol = (t & 3) * 16;
    const half_t* Ag = A + (size_t)(rowBase + sRow) * lda + sCol;
    const half_t* Bg = B + (size_t)(colBase + sRow) * ldb + sCol;

    f32x4 acc[4][2] = {};

    u16x8 pa0 = *(const u16x8*)(Ag);
    u16x8 pa1 = *(const u16x8*)(Ag + 8);
    u16x8 pb0 = *(const u16x8*)(Bg);
    u16x8 pb1 = *(const u16x8*)(Bg + 8);

    const int fr = l & 15;
    const int kg = (l >> 4) * 8;

    for (int k0 = 0; k0 < K; k0 += BK) {
        __syncthreads();
        *(u16x8*)&As[sRow * BKP + sCol]     = pa0;
        *(u16x8*)&As[sRow * BKP + sCol + 8] = pa1;
        *(u16x8*)&Bs[sRow * BKP + sCol]     = pb0;
        *(u16x8*)&Bs[sRow * BKP + sCol + 8] = pb1;
        __syncthreads();
        if (k0 + BK < K) {                 // prefetch next K-tile
            pa0 = *(const u16x8*)(Ag + k0 + BK);
            pa1 = *(const u16x8*)(Ag + k0 + BK + 8);
            pb0 = *(const u16x8*)(Bg + k0 + BK);
            pb1 = *(const u16x8*)(Bg + k0 + BK + 8);
        }
        #pragma unroll
        for (int kk = 0; kk < 2; kk++) {   // two 32-wide k-chunks
            f16x8 a[4], bb[2];
            #pragma unroll
            for (int fm = 0; fm < 4; fm++)
                a[fm] = *(const f16x8*)&As[(wr * 64 + fm * 16 + fr) * BKP + kk * 32 + kg];
            #pragma unroll
            for (int fn = 0; fn < 2; fn++)
                bb[fn] = *(const f16x8*)&Bs[(wc * 32 + fn * 16 + fr) * BKP + kk * 32 + kg];
            #pragma unroll
            for (int fm = 0; fm < 4; fm++)
                #pragma unroll
                for (int fn = 0; fn < 2; fn++)
                    acc[fm][fn] = __builtin_amdgcn_mfma_f32_16x16x32_f16(a[fm], bb[fn], acc[fm][fn], 0, 0, 0);
        }
    }

    // epilogue: C/D layout col=lane&15, row=(lane>>4)*4+reg  [m89-verified]
    #pragma unroll
    for (int fm = 0; fm < 4; fm++) {
        const int r0 = rowBase + wr * 64 + fm * 16 + (l >> 4) * 4;
        #pragma unroll
        for (int fn = 0; fn < 2; fn++) {
            const int c0 = colBase + wc * 32 + fn * 16 + (l & 15);
            #pragma unroll
            for (int r = 0; r < 4; r++) {
                float v = acc[fm][fn][r] * alpha;
                const int rr = r0 + r;
                if (biasMode == 1) v += bias[c0];
                else if (biasMode == 2) v += bias[rr];
                if (gelu_flag) v = 0.5f * v * (1.0f + erff(v * 0.70710678118654752f));
                if (resH) v += (float)resH[(size_t)rr * ldr + c0];
                if (OUT16) ((half_t*)Cout)[(size_t)rr * ldc + c0] = (half_t)v;
                else       ((float*)Cout)[(size_t)rr * ldc + c0] = v;
            }
        }
    }
}

// Batched Q/K/V^T projections, all heads: grid (16, 32, 3).
// z=0: Q_all[2048,4096]; z=1: K_all; z=2: VT_all[4096,2048] (row bias).
__global__ __launch_bounds__(512, 2)
void k_proj(const half_t* __restrict__ xln16,
            const half_t* __restrict__ WqS, const half_t* __restrict__ WkS,
            const half_t* __restrict__ WvS,
            const float* __restrict__ bq, const float* __restrict__ bk,
            const float* __restrict__ bv,
            half_t* __restrict__ Q16, half_t* __restrict__ K16,
            half_t* __restrict__ VT16) {
    const int z = blockIdx.z;
    if (z == 0)
        hgemm_body<1>(blockIdx.x * BM, blockIdx.y * BN, xln16, DIM, WqS, DIM,
                      Q16, HEADS * DIM, DIM, 1.0f, bq, 1, nullptr, 0, 0);
    else if (z == 1)
        hgemm_body<1>(blockIdx.x * BM, blockIdx.y * BN, xln16, DIM, WkS, DIM,
                      K16, HEADS * DIM, DIM, 1.0f, bk, 1, nullptr, 0, 0);
    else
        hgemm_body<1>(blockIdx.y * BM, blockIdx.x * BN, WvS, DIM, xln16, DIM,
                      VT16, N_NODES, DIM, 1.0f, bv, 2, nullptr, 0, 0);
}

// QK^T for head h: S = scale*(Q_h K_h^T) + cb_h. grid (16,16).
__global__ __launch_bounds__(512, 2)
void k_qkt(const half_t* __restrict__ Q16, const half_t* __restrict__ K16,
           float* __restrict__ S, float alpha, const half_t* __restrict__ cb, int h) {
    hgemm_body<0>(blockIdx.x * BM, blockIdx.y * BN,
                  Q16 + h * DIM, HEADS * DIM, K16 + h * DIM, HEADS * DIM,
                  S, N_NODES, DIM, alpha, nullptr, 0, cb, N_NODES, 0);
}

// FF1: ffmid16 = fp16(gelu(h216 @ W1 + b1)). grid (16,16).
__global__ __launch_bounds__(512, 2)
void k_ff1(const half_t* __restrict__ h216, const half_t* __restrict__ W1T16,
           half_t* __restrict__ ffmid16, const float* __restrict__ b1) {
    hgemm_body<1>(blockIdx.x * BM, blockIdx.y * BN, h216, DIM, W1T16, DIM,
                  ffmid16, FFDIM, DIM, 1.0f, b1, 1, nullptr, 0, 1);
}

// Generic split-K=4 into fp32 partial planes [z][2048][512]. grid (16,4,4).
__global__ __launch_bounds__(512, 2)
void k_hsplitk(const half_t* __restrict__ A, int lda, const half_t* __restrict__ B, int ldb,
               float* __restrict__ part, int Kslice, int Koff) {
    const int z = blockIdx.z;
    hgemm_body<0>(blockIdx.x * BM, blockIdx.y * BN,
                  A + (size_t)z * Koff, lda, B + (size_t)z * Koff, ldb,
                  part + (size_t)z * N_NODES * DIM, DIM, Kslice, 1.0f,
                  nullptr, 0, nullptr, 0, 0);
}

// Sum 4 partials (+bias[col], +fp32 residual); dst fp32 or fp16 (ld dstLd).
template<int OUT16>
__device__ __forceinline__
void reduce4_body(const float* __restrict__ part, void* __restrict__ dst, int dstLd,
                  const float* __restrict__ bias, const float* __restrict__ res, int resLd) {
    const size_t q = (size_t)blockIdx.x * 256 + threadIdx.x;   // float4 index
    const size_t CH = (size_t)N_NODES * DIM / 4;
    const float4 a0 = ((const float4*)part)[q];
    const float4 a1 = ((const float4*)part)[q + CH];
    const float4 a2 = ((const float4*)part)[q + 2 * CH];
    const float4 a3 = ((const float4*)part)[q + 3 * CH];
    float4 s;
    s.x = a0.x + a1.x + a2.x + a3.x;
    s.y = a0.y + a1.y + a2.y + a3.y;
    s.z = a0.z + a1.z + a2.z + a3.z;
    s.w = a0.w + a1.w + a2.w + a3.w;
    const size_t el = q * 4;
    const size_t r = el >> 9, c = el & 511;                    // [2048][512]
    if (bias) { s.x += bias[c]; s.y += bias[c + 1]; s.z += bias[c + 2]; s.w += bias[c + 3]; }
    if (res) {
        const float4 rv = *(const float4*)&res[r * resLd + c];
        s.x += rv.x; s.y += rv.y; s.z += rv.z; s.w += rv.w;
    }
    if (OUT16) {
        f16x4 h; h[0] = (half_t)s.x; h[1] = (half_t)s.y; h[2] = (half_t)s.z; h[3] = (half_t)s.w;
        *(f16x4*)&((half_t*)dst)[r * (size_t)dstLd + c] = h;
    } else {
        *(float4*)&((float*)dst)[r * (size_t)dstLd + c] = s;
    }
}

__global__ __launch_bounds__(256)
void k_reduce4_f32(const float* __restrict__ part, float* __restrict__ dst, int dstLd,
                   const float* __restrict__ bias, const float* __restrict__ res, int resLd) {
    reduce4_body<0>(part, dst, dstLd, bias, res, resLd);
}
__global__ __launch_bounds__(256)
void k_reduce4_f16(const float* __restrict__ part, half_t* __restrict__ dst, int dstLd) {
    reduce4_body<1>(part, dst, dstLd, nullptr, nullptr, 0);
}

// ---------------------------------------------------------------------------
// 32x32 tiled transpose fp32 -> fp16: dst[C][R] = fp16(src[R][C]^T)
// ---------------------------------------------------------------------------
__device__ __forceinline__
void transpose16_body(const float* __restrict__ src, half_t* __restrict__ dst, int R, int C) {
    __shared__ float tile[32][33];
    const int t = threadIdx.x;
    const int tx = t & 31, ty = t >> 5;
    const int x0 = blockIdx.x * 32, y0 = blockIdx.y * 32;
    #pragma unroll
    for (int i = 0; i < 4; i++)
        tile[ty + 8 * i][tx] = src[(size_t)(y0 + ty + 8 * i) * C + x0 + tx];
    __syncthreads();
    #pragma unroll
    for (int i = 0; i < 4; i++)
        dst[(size_t)(x0 + ty + 8 * i) * R + y0 + tx] = (half_t)tile[tx][ty + 8 * i];
}

__global__ __launch_bounds__(256)
void k_transpose16(const float* __restrict__ src, half_t* __restrict__ dst, int R, int C) {
    transpose16_body(src, dst, R, C);
}

// Wq/Wk/Wv -> stacked fp16 [h*512+e][d]: z = w*8 + h, each 512x512.
__global__ __launch_bounds__(256)
void k_transpose_qkv16(const float* __restrict__ Wq, const float* __restrict__ Wk,
                       const float* __restrict__ Wv,
                       half_t* __restrict__ WqS, half_t* __restrict__ WkS,
                       half_t* __restrict__ WvS) {
    const int z = blockIdx.z;
    const int w = z >> 3, h = z & 7;
    const float* src = (w == 0 ? Wq : w == 1 ? Wk : Wv) + (size_t)h * DIM * DIM;
    half_t* dst      = (w == 0 ? WqS : w == 1 ? WkS : WvS) + (size_t)h * DIM * DIM;
    transpose16_body(src, dst, DIM, DIM);
}

// ---------------------------------------------------------------------------
// Row softmax: S fp32 in -> P fp16 out.
// ---------------------------------------------------------------------------
__global__ __launch_bounds__(256)
void k_softmax(const float* __restrict__ S, half_t* __restrict__ P) {
    const int i = blockIdx.x;
    const int t = threadIdx.x;
    const int lane = t & 63, wid = t >> 6;
    __shared__ float red[4];

    float v[8];
    float m = -1e30f;
    #pragma unroll
    for (int k = 0; k < 8; k++) {
        v[k] = S[(size_t)i * N_NODES + t + k * 256];
        m = fmaxf(m, v[k]);
    }
    #pragma unroll
    for (int o = 32; o > 0; o >>= 1) m = fmaxf(m, __shfl_xor(m, o));
    if (lane == 0) red[wid] = m;
    __syncthreads();
    m = fmaxf(fmaxf(red[0], red[1]), fmaxf(red[2], red[3]));
    __syncthreads();

    float s = 0.0f;
    #pragma unroll
    for (int k = 0; k < 8; k++) { v[k] = expf(v[k] - m); s += v[k]; }
    #pragma unroll
    for (int o = 32; o > 0; o >>= 1) s += __shfl_xor(s, o);
    if (lane == 0) red[wid] = s;
    __syncthreads();
    s = red[0] + red[1] + red[2] + red[3];
    const float inv = 1.0f / s;
    #pragma unroll
    for (int k = 0; k < 8; k++)
        P[(size_t)i * N_NODES + t + k * 256] = (half_t)(v[k] * inv);
}

// ---------------------------------------------------------------------------
extern "C" void kernel_launch(void* const* d_in, const int* in_sizes, int n_in,
                              void* d_out, int out_size, void* d_ws, size_t ws_size,
                              hipStream_t stream) {
    const float* x         = (const float*)d_in[0];
    const float* edge_attr = (const float*)d_in[1];
    const float* b         = (const float*)d_in[2];
    const int*   path_idx  = (const int*)d_in[3];
    const int*   path_len  = (const int*)d_in[4];
    const float* Wq = (const float*)d_in[5];  const float* bq = (const float*)d_in[6];
    const float* Wk = (const float*)d_in[7];  const float* bk = (const float*)d_in[8];
    const float* Wv = (const float*)d_in[9];  const float* bv = (const float*)d_in[10];
    const float* edge_vec = (const float*)d_in[11];
    const float* Wo = (const float*)d_in[12]; const float* bo = (const float*)d_in[13];
    const float* ln1g = (const float*)d_in[14]; const float* ln1b = (const float*)d_in[15];
    const float* ln2g = (const float*)d_in[16]; const float* ln2b = (const float*)d_in[17];
    const float* W1 = (const float*)d_in[18]; const float* b1 = (const float*)d_in[19];
    const float* W2 = (const float*)d_in[20]; const float* b2 = (const float*)d_in[21];
    float* out = (float*)d_out;

    // ---- workspace layout (float offsets) ----
    float* ws = (float*)d_ws;
    half_t* xln16 = (half_t*)(ws + 0);              // 0.5M fl (2048x512 f16)
    half_t* WqS   = (half_t*)(ws + 524288);         // 1M fl each (4096x512 f16)
    half_t* WkS   = (half_t*)(ws + 1572864);
    half_t* WvS   = (half_t*)(ws + 2621440);
    // overlay after projections (Wstack dead):
    half_t* WoT16 = (half_t*)(ws + 524288);         // 1M fl (512x4096 f16)
    half_t* W1T16 = (half_t*)(ws + 1572864);        // 0.5M fl (2048x512 f16)
    half_t* W2T16 = (half_t*)(ws + 2097152);        // 0.5M fl (512x2048 f16)
    half_t* Q16   = (half_t*)(ws + 3670016);        // 4.2M fl (2048x4096 f16)
    half_t* K16   = (half_t*)(ws + 7864320);        // 4.2M fl
    half_t* VT16  = (half_t*)(ws + 12058624);       // 4.2M fl (4096x2048 f16)
    half_t* d2    = (half_t*)(ws + 16252928);       // 0.5M fl (32768x32 f16)
    float*  S     = ws + 16777216;                  // 4.2M fl fp32
    float*  x1    = ws + 16777216;                  //   overlay after attention
    half_t* h216  = (half_t*)(ws + 17825792);       //   overlay (2048x512 f16)
    half_t* P16   = (half_t*)(ws + 20971520);       // 2.1M fl (2048x2048 f16)
    half_t* mh16  = (half_t*)(ws + 23068672);       // 4.2M fl (2048x4096 f16)
    half_t* ffmid16 = (half_t*)(ws + 23068672);     //   overlay after Wo (2048x2048 f16)
    float*  pvpart = ws + 27262976;                 // 4.2M fl fp32
    half_t* cb    = (half_t*)(ws + 31457280);       // 8 planes: 16.8M fl; 4 planes: 8.4M
    const int big = (ws_size >= (size_t)48234496 * 4);   // 192.9 MB for 8 planes
    (void)in_sizes; (void)n_in; (void)out_size;

    const float scale = 0.04419417382415922f; // 1/sqrt(512)
    const size_t NND4 = (size_t)N_NODES * DIM / 4 / 256; // reduce4 grid

    // 1) LN1 -> fp16; 2) edge table fp16; 3) W transposes -> fp16 stacks
    ln_kernel<<<N_NODES, 256, 0, stream>>>(x, ln1g, ln1b, xln16);
    edge_d_kernel<<<NEDGE / 256, 256, 0, stream>>>(edge_attr, edge_vec, d2);
    k_transpose_qkv16<<<dim3(16, 16, 24), 256, 0, stream>>>(Wq, Wk, Wv, WqS, WkS, WvS);

    // 4) batched projections for ALL heads (1536 blocks)
    k_proj<<<dim3(16, 32, 3), 512, 0, stream>>>(xln16, WqS, WkS, WvS, bq, bk, bv,
                                                Q16, K16, VT16);

    // 5) Wstack dead -> transpose Wo/W1/W2 into its space (fp16)
    k_transpose16<<<dim3(16, 128), 256, 0, stream>>>(Wo, WoT16, HEADS * DIM, DIM);
    k_transpose16<<<dim3(64, 16),  256, 0, stream>>>(W1, W1T16, DIM, FFDIM);
    k_transpose16<<<dim3(16, 64),  256, 0, stream>>>(W2, W2T16, FFDIM, DIM);

    // 6) spatial bias planes
    if (big)
        k_spatial_bias8<<<(int)(NN / 2 / 256), 256, 0, stream>>>(b, path_idx, path_len, d2, cb);

    // 7) per-head attention
    for (int h = 0; h < HEADS; h++) {
        if (!big && (h & 3) == 0)
            k_spatial_bias4<<<(int)(NN / 256), 256, 0, stream>>>(
                b, path_idx, path_len, d2, cb, h >> 2);
        const half_t* cbplane = cb + (size_t)(big ? h : (h & 3)) * NN;

        k_qkt<<<dim3(16, 16), 512, 0, stream>>>(Q16, K16, S, scale, cbplane, h);
        k_softmax<<<N_NODES, 256, 0, stream>>>(S, P16);
        // O_h = P @ V: split-K4 over 2048
        k_hsplitk<<<dim3(16, 4, 4), 512, 0, stream>>>(
            P16, N_NODES, VT16 + (size_t)h * DIM * N_NODES, N_NODES, pvpart, 512, 512);
        k_reduce4_f16<<<(int)NND4, 256, 0, stream>>>(pvpart, mh16 + (size_t)h * DIM, HEADS * DIM);
    }

    // 8) x1 = mh @ Wo + bo + x   (split-K4 over 4096)
    k_hsplitk<<<dim3(16, 4, 4), 512, 0, stream>>>(
        mh16, HEADS * DIM, WoT16, HEADS * DIM, pvpart, 1024, 1024);
    k_reduce4_f32<<<(int)NND4, 256, 0, stream>>>(pvpart, x1, DIM, bo, x, DIM);

    // 9) LN2 -> fp16
    ln_kernel<<<N_NODES, 256, 0, stream>>>(x1, ln2g, ln2b, h216);

    // 10) ffmid = fp16(gelu(h2 @ W1 + b1))  (256 blocks; mh16 dead -> ffmid16)
    k_ff1<<<dim3(16, 16), 512, 0, stream>>>(h216, W1T16, ffmid16, b1);

    // 11) out = ffmid @ W2 + b2 + x1  (split-K4 over 2048)
    k_hsplitk<<<dim3(16, 4, 4), 512, 0, stream>>>(
        ffmid16, FFDIM, W2T16, FFDIM, pvpart, 512, 512);
    k_reduce4_f32<<<(int)NND4, 256, 0, stream>>>(pvpart, out, DIM, b2, x1, DIM);
}